// Round 8
// baseline (1035.189 us; speedup 1.0000x reference)
//
#include <hip/hip_runtime.h>
#include <hip/hip_bf16.h>
#include <math.h>

// Problem constants
#define BB   4
#define SS   1024
#define VV   256
#define KDIM 64
#define HH   8
#define TT   4
#define EPSV 1e-3f
#define SCL  0.125f        // KD^-0.5
#define INV2048 4.8828125e-4f

typedef float f4 __attribute__((ext_vector_type(4)));
typedef short bf8 __attribute__((ext_vector_type(8)));       // 8 bf16
typedef _Float16 h8 __attribute__((ext_vector_type(8)));     // 8 f16
typedef _Float16 h4 __attribute__((ext_vector_type(4)));

#define LDP 68   // fp32 GEMM LDS stride (floats)
#define LHS 68   // split-f16 GEMM LDS stride (halves; 34 dwords -> 2-way, free)

__device__ __forceinline__ short f2bf(float x) {
  __hip_bfloat16 h = __float2bfloat16(x);   // RNE
  return *reinterpret_cast<short*>(&h);
}
__device__ __forceinline__ float bf2f(short h) {
  union { unsigned u; float f; } cv;
  cv.u = ((unsigned)(unsigned short)h) << 16;
  return cv.f;
}

// ---------------------------------------------------------------------------
// identity affine init (t=0 consumers)
// ---------------------------------------------------------------------------
__global__ __launch_bounds__(256) void k_init(float* __restrict__ g, float* __restrict__ b)
{
  int i = blockIdx.x * 256 + threadIdx.x;
  g[i] = 1.f; b[i] = 0.f;
}

// ---------------------------------------------------------------------------
// stats + gamma/beta -> per-column affine (g', b'):  BN(x) = x*g' + b'
// ---------------------------------------------------------------------------
__global__ __launch_bounds__(256) void k_affine(
    const float* __restrict__ st, const float* __restrict__ gamma,
    const float* __restrict__ beta, int t,
    float* __restrict__ ag, float* __restrict__ ab)
{
  int h = blockIdx.x, c = threadIdx.x;
  float s  = st[(h * 256 + c) * 2];
  float s2 = st[(h * 256 + c) * 2 + 1];
  float mean = s * (1.f / 4096.f);
  float var  = s2 * (1.f / 4096.f) - mean * mean;
  float g = gamma[(h * TT + t) * 256 + c] * rsqrtf(var + EPSV);
  ag[h * 256 + c] = g;
  ab[h * 256 + c] = beta[(h * TT + t) * 256 + c] - mean * g;
}

// ---------------------------------------------------------------------------
// fp32 GEMM core (R4, proven) — used only by k_in_dense (1 dispatch).
// ---------------------------------------------------------------------------
__device__ __forceinline__ void gemm_core(
    const float* __restrict__ A, const float* __restrict__ Bm, int ldb,
    float acc[4][4], float (*As)[LDP], float (*Bs)[LDP])
{
  const int tid = threadIdx.x;
  const int tx = tid & 15, ty = tid >> 4;
#pragma unroll
  for (int i = 0; i < 4; i++)
#pragma unroll
    for (int j = 0; j < 4; j++) acc[i][j] = 0.f;

  for (int k0 = 0; k0 < 256; k0 += 16) {
#pragma unroll
    for (int l = 0; l < 4; l++) {
      int e = tid + l * 256;
      int r = e >> 4, kk = e & 15;
      As[kk][r] = A[r * 256 + k0 + kk];
      int rb = e >> 6, nn = e & 63;
      Bs[rb][nn] = Bm[(k0 + rb) * ldb + nn];
    }
    __syncthreads();
#pragma unroll
    for (int kk = 0; kk < 16; kk++) {
      f4 av = *(const f4*)&As[kk][ty * 4];
      f4 bv = *(const f4*)&Bs[kk][tx * 4];
#pragma unroll
      for (int i = 0; i < 4; i++)
#pragma unroll
        for (int j = 0; j < 4; j++)
          acc[i][j] += av[i] * bv[j];
    }
    __syncthreads();
  }
}

// ---------------------------------------------------------------------------
// net0 = x @ W_in, broadcast into all H head slots (R4 verbatim)
// ---------------------------------------------------------------------------
__global__ __launch_bounds__(256) void k_in_dense(
    const float* __restrict__ x, const float* __restrict__ Win,
    float* __restrict__ net)
{
  __shared__ __align__(16) float As[16][LDP];
  __shared__ __align__(16) float Bs[16][LDP];
  const int mt = blockIdx.x, nt = blockIdx.y;
  float acc[4][4];
  gemm_core(x + mt * 64 * 256, Win + nt * 64, 256, acc, As, Bs);
  const int tx = threadIdx.x & 15, ty = threadIdx.x >> 4;
#pragma unroll
  for (int i = 0; i < 4; i++) {
    f4 v;
#pragma unroll
    for (int j = 0; j < 4; j++) v[j] = acc[i][j];
    int row = mt * 64 + ty * 4 + i;
    int col = nt * 64 + tx * 4;
    for (int h = 0; h < HH; h++)
      *(f4*)&net[(size_t)h * 1048576 + row * 256 + col] = v;
  }
}

// ---------------------------------------------------------------------------
// Weight prep (per t): transpose + split into f16 hi/lo, layout [n][k(256)].
// ---------------------------------------------------------------------------
__global__ __launch_bounds__(256) void k_prep(
    const float* __restrict__ Wq, const float* __restrict__ Wk,
    const float* __restrict__ Wv, const float* __restrict__ Wd,
    _Float16* __restrict__ oh, _Float16* __restrict__ ol, int t)
{
  __shared__ __align__(16) _Float16 Th[64][LHS];
  __shared__ __align__(16) _Float16 Tl[64][LHS];
  const int xb = blockIdx.x, kb = blockIdx.y, h = blockIdx.z;
  const int tid = threadIdx.x;
  const float* src; int N, nb; size_t dbase;
  if (xb == 0)      { src = Wq; N = 64;  nb = 0;      dbase = (size_t)h * 16384; }
  else if (xb == 1) { src = Wk; N = 64;  nb = 0;      dbase = 131072 + (size_t)h * 16384; }
  else if (xb < 6)  { src = Wv; N = 256; nb = xb - 2; dbase = 262144 + (size_t)h * 65536; }
  else              { src = Wd; N = 256; nb = xb - 6; dbase = 786432 + (size_t)h * 65536; }
  src += (size_t)(h * TT + t) * 256 * N;
#pragma unroll
  for (int i = 0; i < 4; i++) {
    int fi = tid + i * 256;
    int r = fi >> 4, c4 = fi & 15;
    f4 w = *(const f4*)&src[(size_t)(kb * 64 + r) * N + nb * 64 + c4 * 4];
    h4 hv, lv;
#pragma unroll
    for (int j = 0; j < 4; j++) {
      _Float16 hi = (_Float16)w[j];
      hv[j] = hi;
      lv[j] = (_Float16)((w[j] - (float)hi) * 2048.f);
    }
    *(h4*)&Th[r][c4 * 4] = hv;
    *(h4*)&Tl[r][c4 * 4] = lv;
  }
  __syncthreads();
#pragma unroll
  for (int i = 0; i < 4; i++) {
    int fo = tid + i * 256;
    int nr = fo >> 4, k4 = fo & 15;
    h4 hv, lv;
#pragma unroll
    for (int j = 0; j < 4; j++) { hv[j] = Th[k4 * 4 + j][nr]; lv[j] = Tl[k4 * 4 + j][nr]; }
    size_t d = dbase + (size_t)(nb * 64 + nr) * 256 + kb * 64 + k4 * 4;
    *(h4*)&oh[d] = hv;
    *(h4*)&ol[d] = lv;
  }
}

// ---------------------------------------------------------------------------
// A-tile staging with on-the-fly per-column affine (BN fold):
// issue loads to regs (+fma), split+write to LDS later.
// ---------------------------------------------------------------------------
__device__ __forceinline__ void stage_issue_aff(
    const float* __restrict__ A, const float* __restrict__ ag,
    const float* __restrict__ ab, int kc, int tid, f4 w[4])
{
#pragma unroll
  for (int i = 0; i < 4; i++) {
    int fi = tid + i * 256;
    int r = fi >> 4, c4 = fi & 15;
    f4 raw = *(const f4*)&A[(size_t)r * 256 + kc * 64 + c4 * 4];
    f4 g = *(const f4*)&ag[kc * 64 + c4 * 4];
    f4 b = *(const f4*)&ab[kc * 64 + c4 * 4];
#pragma unroll
    for (int j = 0; j < 4; j++) w[i][j] = fmaf(raw[j], g[j], b[j]);
  }
}
__device__ __forceinline__ void stage_write(
    const f4 w[4], int tid, _Float16 (*Ah)[LHS], _Float16 (*Al)[LHS])
{
#pragma unroll
  for (int i = 0; i < 4; i++) {
    int fi = tid + i * 256;
    int r = fi >> 4, c4 = fi & 15;
    h4 hv, lv;
#pragma unroll
    for (int j = 0; j < 4; j++) {
      _Float16 hi = (_Float16)w[i][j];
      hv[j] = hi;
      lv[j] = (_Float16)((w[i][j] - (float)hi) * 2048.f);
    }
    *(h4*)&Ah[r][c4 * 4] = hv;
    *(h4*)&Al[r][c4 * 4] = lv;
  }
}

// ---------------------------------------------------------------------------
// QKV GEMM (merged): A = affine(net) staged once per half, dbuf + prefetch.
// grid (64 mt, 8 h).
// ---------------------------------------------------------------------------
__global__ __launch_bounds__(256) void k_mm_qkv(
    const float* __restrict__ net,
    const float* __restrict__ affg, const float* __restrict__ affb,
    const _Float16* __restrict__ wph, const _Float16* __restrict__ wpl,
    _Float16* __restrict__ qph, _Float16* __restrict__ qpl,
    _Float16* __restrict__ kph, _Float16* __restrict__ kpl,
    short* __restrict__ vth, short* __restrict__ vtl)
{
  __shared__ __align__(16) _Float16 Ah[2][64][LHS];
  __shared__ __align__(16) _Float16 Al[2][64][LHS];
  const int mt = blockIdx.x, h = blockIdx.y;
  const int tid = threadIdx.x, wv = tid >> 6, lane = tid & 63;
  const int ln = lane & 15, quad = lane >> 4;
  const float* A = net + (size_t)h * 1048576 + (size_t)mt * 64 * 256;
  const float* ag = affg + h * 256;
  const float* ab = affb + h * 256;

  for (int half = 0; half < 2; half++) {
    size_t bb[3];
#pragma unroll
    for (int j = 0; j < 3; j++) {
      int nt = half * 3 + j;
      if (nt == 0)      bb[j] = (size_t)h * 16384;
      else if (nt == 1) bb[j] = 131072 + (size_t)h * 16384;
      else              bb[j] = 262144 + (size_t)h * 65536 + (size_t)(nt - 2) * 16384;
      bb[j] += (size_t)(wv * 16 + ln) * 256;
    }

    f4 mn[3][4], cr[3][4];
#pragma unroll
    for (int j = 0; j < 3; j++)
#pragma unroll
      for (int mf = 0; mf < 4; mf++) {
        mn[j][mf] = (f4){0.f, 0.f, 0.f, 0.f};
        cr[j][mf] = (f4){0.f, 0.f, 0.f, 0.f};
      }

    f4 w[4];
    stage_issue_aff(A, ag, ab, 0, tid, w);
    stage_write(w, tid, Ah[0], Al[0]);
    __syncthreads();

    for (int kc = 0; kc < 4; kc++) {
      const int buf = kc & 1;
      if (kc < 3) stage_issue_aff(A, ag, ab, kc + 1, tid, w);
#pragma unroll
      for (int j = 0; j < 3; j++) {
        const _Float16* bh = wph + bb[j] + kc * 64;
        const _Float16* bl = wpl + bb[j] + kc * 64;
        h8 bh0 = *(const h8*)&bh[quad * 8];
        h8 bh1 = *(const h8*)&bh[32 + quad * 8];
        h8 bl0 = *(const h8*)&bl[quad * 8];
        h8 bl1 = *(const h8*)&bl[32 + quad * 8];
#pragma unroll
        for (int mf = 0; mf < 4; mf++) {
          h8 ah0 = *(const h8*)&Ah[buf][mf * 16 + ln][quad * 8];
          h8 ah1 = *(const h8*)&Ah[buf][mf * 16 + ln][32 + quad * 8];
          h8 al0 = *(const h8*)&Al[buf][mf * 16 + ln][quad * 8];
          h8 al1 = *(const h8*)&Al[buf][mf * 16 + ln][32 + quad * 8];
          mn[j][mf] = __builtin_amdgcn_mfma_f32_16x16x32_f16(ah0, bh0, mn[j][mf], 0, 0, 0);
          mn[j][mf] = __builtin_amdgcn_mfma_f32_16x16x32_f16(ah1, bh1, mn[j][mf], 0, 0, 0);
          cr[j][mf] = __builtin_amdgcn_mfma_f32_16x16x32_f16(ah0, bl0, cr[j][mf], 0, 0, 0);
          cr[j][mf] = __builtin_amdgcn_mfma_f32_16x16x32_f16(ah1, bl1, cr[j][mf], 0, 0, 0);
          cr[j][mf] = __builtin_amdgcn_mfma_f32_16x16x32_f16(al0, bh0, cr[j][mf], 0, 0, 0);
          cr[j][mf] = __builtin_amdgcn_mfma_f32_16x16x32_f16(al1, bh1, cr[j][mf], 0, 0, 0);
        }
      }
      if (kc < 3) stage_write(w, tid, Ah[buf ^ 1], Al[buf ^ 1]);
      __syncthreads();
    }

#pragma unroll
    for (int j = 0; j < 3; j++) {
      int nt = half * 3 + j;
      if (nt <= 1) {
        _Float16* dh = (nt == 0) ? qph : kph;
        _Float16* dl = (nt == 0) ? qpl : kpl;
        int col = wv * 16 + ln;
#pragma unroll
        for (int mf = 0; mf < 4; mf++)
#pragma unroll
          for (int r = 0; r < 4; r++) {
            int row = mt * 64 + mf * 16 + quad * 4 + r;
            int b_ = row >> 10, sI = row & 1023;
            float v = mn[j][mf][r] + cr[j][mf][r] * INV2048;
            _Float16 hi = (_Float16)v;
            size_t idx = ((size_t)(h * 4 + b_) * 1024 + sI) * 64 + col;
            dh[idx] = hi;
            dl[idx] = (_Float16)((v - (float)hi) * 2048.f);
          }
      } else {
        int c = (nt - 2) * 64 + wv * 16 + ln;
#pragma unroll
        for (int mf = 0; mf < 4; mf++)
#pragma unroll
          for (int r = 0; r < 4; r++) {
            int row = mt * 64 + mf * 16 + quad * 4 + r;
            int b_ = row >> 10, sI = row & 1023;
            float v = mn[j][mf][r] + cr[j][mf][r] * INV2048;
            short hi = f2bf(v);
            size_t idx = ((size_t)(h * 4 + b_) * 256 + c) * 1024 + sI;
            vth[idx] = hi;
            vtl[idx] = f2bf(v - bf2f(hi));
          }
      }
    }
  }
}

// ---------------------------------------------------------------------------
// Dense GEMM (merged) + fused BN1-apply + residual + BN2-stats:
// A = affine1(buf1); epilogue y2 = affine1(buf1) + relu(mm) -> buf2, stats2.
// grid (64 mt, 8 h).
// ---------------------------------------------------------------------------
__global__ __launch_bounds__(256) void k_mm_dense(
    const float* __restrict__ buf1,
    const float* __restrict__ affg, const float* __restrict__ affb,
    const _Float16* __restrict__ wph, const _Float16* __restrict__ wpl,
    float* __restrict__ buf2, float* __restrict__ st)
{
  __shared__ __align__(16) _Float16 Ah[2][64][LHS];
  __shared__ __align__(16) _Float16 Al[2][64][LHS];
  const int mt = blockIdx.x, h = blockIdx.y;
  const int tid = threadIdx.x, wv = tid >> 6, lane = tid & 63;
  const int ln = lane & 15, quad = lane >> 4;
  const float* a1 = buf1 + (size_t)h * 1048576;
  float* o2 = buf2 + (size_t)h * 1048576;
  const float* A = a1 + (size_t)mt * 64 * 256;
  const float* ag = affg + h * 256;
  const float* ab = affb + h * 256;

  for (int half = 0; half < 2; half++) {
    size_t bb[2];
#pragma unroll
    for (int j = 0; j < 2; j++) {
      int nt = half * 2 + j;
      bb[j] = 786432 + (size_t)h * 65536 + (size_t)nt * 16384
            + (size_t)(wv * 16 + ln) * 256;
    }

    f4 mn[2][4], cr[2][4];
#pragma unroll
    for (int j = 0; j < 2; j++)
#pragma unroll
      for (int mf = 0; mf < 4; mf++) {
        mn[j][mf] = (f4){0.f, 0.f, 0.f, 0.f};
        cr[j][mf] = (f4){0.f, 0.f, 0.f, 0.f};
      }

    f4 w[4];
    stage_issue_aff(A, ag, ab, 0, tid, w);
    stage_write(w, tid, Ah[0], Al[0]);
    __syncthreads();

    for (int kc = 0; kc < 4; kc++) {
      const int buf = kc & 1;
      if (kc < 3) stage_issue_aff(A, ag, ab, kc + 1, tid, w);
#pragma unroll
      for (int j = 0; j < 2; j++) {
        const _Float16* bh = wph + bb[j] + kc * 64;
        const _Float16* bl = wpl + bb[j] + kc * 64;
        h8 bh0 = *(const h8*)&bh[quad * 8];
        h8 bh1 = *(const h8*)&bh[32 + quad * 8];
        h8 bl0 = *(const h8*)&bl[quad * 8];
        h8 bl1 = *(const h8*)&bl[32 + quad * 8];
#pragma unroll
        for (int mf = 0; mf < 4; mf++) {
          h8 ah0 = *(const h8*)&Ah[buf][mf * 16 + ln][quad * 8];
          h8 ah1 = *(const h8*)&Ah[buf][mf * 16 + ln][32 + quad * 8];
          h8 al0 = *(const h8*)&Al[buf][mf * 16 + ln][quad * 8];
          h8 al1 = *(const h8*)&Al[buf][mf * 16 + ln][32 + quad * 8];
          mn[j][mf] = __builtin_amdgcn_mfma_f32_16x16x32_f16(ah0, bh0, mn[j][mf], 0, 0, 0);
          mn[j][mf] = __builtin_amdgcn_mfma_f32_16x16x32_f16(ah1, bh1, mn[j][mf], 0, 0, 0);
          cr[j][mf] = __builtin_amdgcn_mfma_f32_16x16x32_f16(ah0, bl0, cr[j][mf], 0, 0, 0);
          cr[j][mf] = __builtin_amdgcn_mfma_f32_16x16x32_f16(ah1, bl1, cr[j][mf], 0, 0, 0);
          cr[j][mf] = __builtin_amdgcn_mfma_f32_16x16x32_f16(al0, bh0, cr[j][mf], 0, 0, 0);
          cr[j][mf] = __builtin_amdgcn_mfma_f32_16x16x32_f16(al1, bh1, cr[j][mf], 0, 0, 0);
        }
      }
      if (kc < 3) stage_write(w, tid, Ah[buf ^ 1], Al[buf ^ 1]);
      __syncthreads();
    }

#pragma unroll
    for (int j = 0; j < 2; j++) {
      int nt = half * 2 + j;
      int col = nt * 64 + wv * 16 + ln;
      float gc = ag[col], bc = ab[col];
      float s1 = 0.f, s2 = 0.f;
#pragma unroll
      for (int mf = 0; mf < 4; mf++)
#pragma unroll
        for (int r = 0; r < 4; r++) {
          int row = mt * 64 + mf * 16 + quad * 4 + r;
          size_t idx = (size_t)row * 256 + col;
          float v = mn[j][mf][r] + cr[j][mf][r] * INV2048;
          float yv = fmaf(a1[idx], gc, bc) + fmaxf(v, 0.f);
          o2[idx] = yv;
          s1 += yv; s2 += yv * yv;
        }
      s1 += __shfl_xor(s1, 16, 64); s1 += __shfl_xor(s1, 32, 64);
      s2 += __shfl_xor(s2, 16, 64); s2 += __shfl_xor(s2, 32, 64);
      if (quad == 0) {
        atomicAdd(&st[(h * 256 + col) * 2],     s1);
        atomicAdd(&st[(h * 256 + col) * 2 + 1], s2);
      }
    }
  }
}

// ---------------------------------------------------------------------------
// Flash attention v9: V-column-band split doubles the grid (512 -> 1024
// blocks; the old grid capped occupancy at 2 blocks/CU regardless of
// LDS/VGPR). Block (qt, vc) handles vcols [vc*128, vc*128+128): QK^T +
// softmax are recomputed per band (bit-identical), PV/V-staging halve.
// K/P LDS overlay kept (48 KB -> 3 blocks/CU). 4 barriers/kt.
// grid (32 = qt*2+vc, 4 batch, 8 heads)
// ---------------------------------------------------------------------------
__global__ __launch_bounds__(256, 2) void k_attn(
    const _Float16* __restrict__ qfh, const _Float16* __restrict__ qfl,
    const _Float16* __restrict__ kfh, const _Float16* __restrict__ kfl,
    const short* __restrict__ vth, const short* __restrict__ vtl,
    const float* __restrict__ resid,
    const float* __restrict__ affg, const float* __restrict__ affb,
    float* __restrict__ st, float* __restrict__ obuf)
{
  // AB0: Kh <-> Ph ; AB1: Kl <-> Pl  (8 KB each, swizzled [64][64])
  __shared__ __align__(16) short AB0[64][64];     // 8 KB
  __shared__ __align__(16) short AB1[64][64];     // 8 KB
  __shared__ __align__(16) short VhS[2][64][64];  // 16 KB
  __shared__ __align__(16) short VlS[2][64][64];  // 16 KB  => 48 KB total

  const int qt = blockIdx.x >> 1, vcb = blockIdx.x & 1;
  const int b = blockIdx.y, h = blockIdx.z;
  const int tid = threadIdx.x;
  const int wv = tid >> 6, lane = tid & 63, ln = lane & 15, quad = lane >> 4;
  const int hb = h * 4 + b;
  const int swz = (ln & 7) << 3;

  const _Float16* qgh = qfh + ((size_t)hb * 1024 + qt * 64 + wv * 16 + ln) * 64;
  const _Float16* qgl = qfl + ((size_t)hb * 1024 + qt * 64 + wv * 16 + ln) * 64;
  h8 aqh0 = *(const h8*)&qgh[quad * 8];
  h8 aqh1 = *(const h8*)&qgh[32 + quad * 8];
  h8 aql0 = *(const h8*)&qgl[quad * 8];
  h8 aql1 = *(const h8*)&qgl[32 + quad * 8];

  const _Float16* kgh = kfh + (size_t)hb * 65536;   // [1024 s][64 kd]
  const _Float16* kgl = kfl + (size_t)hb * 65536;
  // own 128-vcol band
  const short* vhg = vth + (size_t)hb * 262144 + (size_t)(vcb * 128) * 1024;
  const short* vlg = vtl + (size_t)hb * 262144 + (size_t)(vcb * 128) * 1024;

  float m[4] = {-1e30f, -1e30f, -1e30f, -1e30f};
  float l[4] = {0.f, 0.f, 0.f, 0.f};
  f4 O[8];
#pragma unroll
  for (int nt = 0; nt < 8; nt++) O[nt] = (f4){0.f, 0.f, 0.f, 0.f};

  // ---- prologue: stage K(0) into AB and V(kt=0, chunk 0) into buf 0 ----
#pragma unroll
  for (int i = 0; i < 2; i++) {
    int e = tid + i * 256;
    int r = e >> 3, c8 = e & 7;
    int cc = (c8 * 8) ^ ((r & 7) << 3);
    *(h8*)&AB0[r][cc] = *(const h8*)&kgh[(size_t)r * 64 + c8 * 8];
    *(h8*)&AB1[r][cc] = *(const h8*)&kgl[(size_t)r * 64 + c8 * 8];
  }
#pragma unroll
  for (int i = 0; i < 2; i++) {
    int e = tid + i * 256;
    int vc = e >> 3, fc = e & 7;
    int cc = (fc * 8) ^ ((vc & 7) << 3);
    size_t g = (size_t)vc * 1024 + fc * 8;
    *(bf8*)&VhS[0][vc][cc] = *(const bf8*)&vhg[g];
    *(bf8*)&VlS[0][vc][cc] = *(const bf8*)&vlg[g];
  }
  __syncthreads();

  for (int kt = 0; kt < 16; kt++) {
    // ---- QK^T: K frags from AB (swizzled) ----
    f4 sv[4];
#pragma unroll
    for (int nf = 0; nf < 4; nf++) {
      int row = nf * 16 + ln;
      h8 bkh0 = *(const h8*)&AB0[row][(quad * 8) ^ swz];
      h8 bkh1 = *(const h8*)&AB0[row][(32 + quad * 8) ^ swz];
      h8 bkl0 = *(const h8*)&AB1[row][(quad * 8) ^ swz];
      h8 bkl1 = *(const h8*)&AB1[row][(32 + quad * 8) ^ swz];
      f4 mn = (f4){0.f, 0.f, 0.f, 0.f};
      f4 cr = (f4){0.f, 0.f, 0.f, 0.f};
      mn = __builtin_amdgcn_mfma_f32_16x16x32_f16(aqh0, bkh0, mn, 0, 0, 0);
      mn = __builtin_amdgcn_mfma_f32_16x16x32_f16(aqh1, bkh1, mn, 0, 0, 0);
      cr = __builtin_amdgcn_mfma_f32_16x16x32_f16(aqh0, bkl0, cr, 0, 0, 0);
      cr = __builtin_amdgcn_mfma_f32_16x16x32_f16(aqh1, bkl1, cr, 0, 0, 0);
      cr = __builtin_amdgcn_mfma_f32_16x16x32_f16(aql0, bkh0, cr, 0, 0, 0);
      cr = __builtin_amdgcn_mfma_f32_16x16x32_f16(aql1, bkh1, cr, 0, 0, 0);
#pragma unroll
      for (int r = 0; r < 4; r++) sv[nf][r] = (mn[r] + cr[r] * INV2048) * SCL;
    }

    // barrier: all waves done READING K before P overwrites the region.
    __syncthreads();   // B1

    // ---- online softmax with defer-max (T13, THR=8) ----
    float mloc[4];
#pragma unroll
    for (int r = 0; r < 4; r++) {
      float v0 = fmaxf(fmaxf(sv[0][r], sv[1][r]), fmaxf(sv[2][r], sv[3][r]));
#pragma unroll
      for (int d = 1; d < 16; d <<= 1)
        v0 = fmaxf(v0, __shfl_xor(v0, d, 64));
      mloc[r] = v0;
    }
    float growth = fmaxf(fmaxf(mloc[0] - m[0], mloc[1] - m[1]),
                         fmaxf(mloc[2] - m[2], mloc[3] - m[3]));
    if (__any(growth > 8.f)) {
      float alpha[4];
#pragma unroll
      for (int r = 0; r < 4; r++) {
        float mnew = fmaxf(m[r], mloc[r]);
        alpha[r] = __expf(m[r] - mnew);
        m[r] = mnew;
        l[r] *= alpha[r];
      }
#pragma unroll
      for (int nt = 0; nt < 8; nt++)
#pragma unroll
        for (int i = 0; i < 4; i++) O[nt][i] *= alpha[i];
    }
#pragma unroll
    for (int r = 0; r < 4; r++) {
      float ls = 0.f;
#pragma unroll
      for (int nf = 0; nf < 4; nf++) {
        float p = __expf(sv[nf][r] - m[r]);
        sv[nf][r] = p;
        ls += p;
      }
#pragma unroll
      for (int d = 1; d < 16; d <<= 1) ls += __shfl_xor(ls, d, 64);
      l[r] += ls;
    }

    // ---- publish P into AB (swizzled; own rows) ----
#pragma unroll
    for (int nf = 0; nf < 4; nf++)
#pragma unroll
      for (int r = 0; r < 4; r++) {
        int row = wv * 16 + quad * 4 + r;
        int c = (nf * 16 + ln) ^ ((row & 7) << 3);
        float p = sv[nf][r];
        short hi = f2bf(p);
        AB0[row][c] = hi;
        AB1[row][c] = f2bf(p - bf2f(hi));
      }
    __syncthreads();   // B2: P ready

    // ---- P fragments (own 16 rows); AB dead for P after this ----
    bf8 ph0 = *(const bf8*)&AB0[wv * 16 + ln][(quad * 8) ^ swz];
    bf8 ph1 = *(const bf8*)&AB0[wv * 16 + ln][(32 + quad * 8) ^ swz];
    bf8 pl0 = *(const bf8*)&AB1[wv * 16 + ln][(quad * 8) ^ swz];
    bf8 pl1 = *(const bf8*)&AB1[wv * 16 + ln][(32 + quad * 8) ^ swz];

    for (int c4 = 0; c4 < 2; c4++) {
      const int buf = c4 & 1;
      const bool haveNext = (c4 < 1) || (kt < 15);
      const int nkt = (c4 < 1) ? kt : kt + 1;
      const int nc4 = (c4 < 1) ? 1 : 0;
      const bool pfK = (c4 == 1) && (kt < 15);

      const int vc0 = tid >> 3, fc0 = tid & 7;
      const int vc1 = vc0 + 32;
      bf8 fvh0, fvh1, fvl0, fvl1;
      if (haveNext) {
        size_t g0 = (size_t)(nc4 * 64 + vc0) * 1024 + nkt * 64 + fc0 * 8;
        size_t g1 = (size_t)(nc4 * 64 + vc1) * 1024 + nkt * 64 + fc0 * 8;
        fvh0 = *(const bf8*)&vhg[g0]; fvl0 = *(const bf8*)&vlg[g0];
        fvh1 = *(const bf8*)&vhg[g1]; fvl1 = *(const bf8*)&vlg[g1];
      }
      h8 fkh0, fkh1, fkl0, fkl1;
      if (pfK) {
        size_t g0 = (size_t)((kt + 1) * 64 + vc0) * 64 + fc0 * 8;
        size_t g1 = (size_t)((kt + 1) * 64 + vc1) * 64 + fc0 * 8;
        fkh0 = *(const h8*)&kgh[g0]; fkl0 = *(const h8*)&kgl[g0];
        fkh1 = *(const h8*)&kgh[g1]; fkl1 = *(const h8*)&kgl[g1];
      }

#pragma unroll
      for (int n2 = 0; n2 < 4; n2++) {
        int nt = c4 * 4 + n2;
        int vrow = n2 * 16 + ln;
        bf8 vh0 = *(const bf8*)&VhS[buf][vrow][(quad * 8) ^ swz];
        bf8 vh1 = *(const bf8*)&VhS[buf][vrow][(32 + quad * 8) ^ swz];
        bf8 vl0 = *(const bf8*)&VlS[buf][vrow][(quad * 8) ^ swz];
        bf8 vl1 = *(const bf8*)&VlS[buf][vrow][(32 + quad * 8) ^ swz];
        O[nt] = __builtin_amdgcn_mfma_f32_16x16x32_bf16(ph0, vh0, O[nt], 0, 0, 0);
        O[nt] = __builtin_amdgcn_mfma_f32_16x16x32_bf16(ph1, vh1, O[nt], 0, 0, 0);
        O[nt] = __builtin_amdgcn_mfma_f32_16x16x32_bf16(ph0, vl0, O[nt], 0, 0, 0);
        O[nt] = __builtin_amdgcn_mfma_f32_16x16x32_bf16(ph1, vl1, O[nt], 0, 0, 0);
        O[nt] = __builtin_amdgcn_mfma_f32_16x16x32_bf16(pl0, vh0, O[nt], 0, 0, 0);
        O[nt] = __builtin_amdgcn_mfma_f32_16x16x32_bf16(pl1, vh1, O[nt], 0, 0, 0);
      }

      if (haveNext) {
        int cc0 = (fc0 * 8) ^ ((vc0 & 7) << 3);
        int cc1 = (fc0 * 8) ^ ((vc1 & 7) << 3);
        *(bf8*)&VhS[buf ^ 1][vc0][cc0] = fvh0;
        *(bf8*)&VlS[buf ^ 1][vc0][cc0] = fvl0;
        *(bf8*)&VhS[buf ^ 1][vc1][cc1] = fvh1;
        *(bf8*)&VlS[buf ^ 1][vc1][cc1] = fvl1;
      }
      if (pfK) {
        // safe: every wave's P-frag reads happened before B3[0]; we are
        // past B3[0], so AB is dead for P and free for K(kt+1).
        int cc0 = (fc0 * 8) ^ ((vc0 & 7) << 3);
        int cc1 = (fc0 * 8) ^ ((vc1 & 7) << 3);
        *(h8*)&AB0[vc0][cc0] = fkh0;
        *(h8*)&AB1[vc0][cc0] = fkl0;
        *(h8*)&AB0[vc1][cc1] = fkh1;
        *(h8*)&AB1[vc1][cc1] = fkl1;
      }
      __syncthreads();   // B3[c4]
    }
  }

  // ---- fused epilogue: y1 = affine(resid) + O/l -> buf1; BN1 stats ----
  // own 128-col band: cols [vcb*128, vcb*128+128)
  const float* rg = affg + h * 256 + vcb * 128;
  const float* rb = affb + h * 256 + vcb * 128;
  const float* rs = resid + (size_t)h * 1048576
                  + (size_t)(b * 1024 + qt * 64 + wv * 16 + quad * 4) * 256
                  + vcb * 128;
  float* ds = obuf + (size_t)h * 1048576
            + (size_t)(b * 1024 + qt * 64 + wv * 16 + quad * 4) * 256
            + vcb * 128;
  float linv[4];
#pragma unroll
  for (int r = 0; r < 4; r++) linv[r] = 1.f / l[r];

  float* S1 = (float*)&AB0[0][0];   // AB free after the loop (4x128 floats)
  float* S2 = (float*)&AB1[0][0];
#pragma unroll
  for (int nt = 0; nt < 8; nt++) {
    int c = nt * 16 + ln;           // local col in [0,128)
    float gc = rg[c], bc = rb[c];
    float s1 = 0.f, s2 = 0.f;
#pragma unroll
    for (int r = 0; r < 4; r++) {
      float yv = fmaf(rs[r * 256 + c], gc, bc) + O[nt][r] * linv[r];
      ds[r * 256 + c] = yv;
      s1 += yv; s2 += yv * yv;
    }
    s1 += __shfl_xor(s1, 16, 64); s1 += __shfl_xor(s1, 32, 64);
    s2 += __shfl_xor(s2, 16, 64); s2 += __shfl_xor(s2, 32, 64);
    if (quad == 0) { S1[wv * 128 + c] = s1; S2[wv * 128 + c] = s2; }
  }
  __syncthreads();
  if (tid < 128) {
    float a1 = S1[tid] + S1[128 + tid] + S1[256 + tid] + S1[384 + tid];
    float a2 = S2[tid] + S2[128 + tid] + S2[256 + tid] + S2[384 + tid];
    atomicAdd(&st[(h * 256 + vcb * 128 + tid) * 2],     a1);
    atomicAdd(&st[(h * 256 + vcb * 128 + tid) * 2 + 1], a2);
  }
}

// ---------------------------------------------------------------------------
// BN apply (final t only: transposed output)
// ---------------------------------------------------------------------------
__global__ __launch_bounds__(256) void k_bnapply(
    const float* __restrict__ a, const float* __restrict__ b,
    const float* __restrict__ stats,
    const float* __restrict__ gamma, const float* __restrict__ beta,
    float* __restrict__ dst, int t, int addB, int transposed)
{
  const int h = blockIdx.y, r0 = blockIdx.x * 64, c = threadIdx.x;
  float s  = stats[(h * 256 + c) * 2];
  float s2 = stats[(h * 256 + c) * 2 + 1];
  float mean = s * (1.f / 4096.f);
  float var  = s2 * (1.f / 4096.f) - mean * mean;
  float inv  = rsqrtf(var + EPSV);
  float g  = gamma[(h * TT + t) * 256 + c] * inv;
  float bt = beta[(h * TT + t) * 256 + c];
  const float* pa = a + (size_t)h * 1048576 + r0 * 256 + c;
  const float* pb = addB ? (b + (size_t)h * 1048576 + r0 * 256 + c) : nullptr;
  for (int r = 0; r < 64; r++) {
    float y = pa[r * 256];
    if (addB) y += pb[r * 256];
    float o = (y - mean) * g + bt;
    int rg = r0 + r;
    if (transposed) dst[((size_t)rg * HH + h) * 256 + c] = o;
    else            dst[(size_t)h * 1048576 + rg * 256 + c] = o;
  }
}

// ---------------------------------------------------------------------------
extern "C" void kernel_launch(void* const* d_in, const int* in_sizes, int n_in,
                              void* d_out, int out_size, void* d_ws, size_t ws_size,
                              hipStream_t stream)
{
  const float* x   = (const float*)d_in[0];
  const float* Win = (const float*)d_in[1];
  const float* Wq  = (const float*)d_in[2];
  const float* Wk  = (const float*)d_in[3];
  const float* Wv  = (const float*)d_in[4];
  const float* Wd  = (const float*)d_in[5];
  const float* g1  = (const float*)d_in[6];
  const float* b1  = (const float*)d_in[7];
  const float* g2  = (const float*)d_in[8];
  const float* b2  = (const float*)d_in[9];
  float* out = (float*)d_out;
  float* ws  = (float*)d_ws;

  float* net   = ws;                       // buf2: pre-BN2 state (or net0)
  float* tmp   = net + 8388608;            // buf1: pre-BN1 state (y1)
  float* stats = tmp + 8388608;            // 2 phases * H*V*2 = 8192 f
  float* affg1 = stats + 8192;             // 2048 f each
  float* affb1 = affg1 + 2048;
  float* affg2 = affb1 + 2048;
  float* affb2 = affg2 + 2048;
  float* affgI = affb2 + 2048;
  float* affbI = affgI + 2048;             // ends at stats+20480 < stats+32768
  _Float16* qph = (_Float16*)(stats + 32768);  // 2,097,152 h
  _Float16* qpl = qph + 2097152;
  _Float16* kph = qpl + 2097152;
  _Float16* kpl = kph + 2097152;
  short* vth   = (short*)(kpl + 2097152);
  short* vtl   = vth + 8388608;
  _Float16* wph = (_Float16*)(vtl + 8388608);
  _Float16* wpl = wph + 1310720;

  k_init<<<dim3(8), 256, 0, stream>>>(affgI, affbI);
  k_in_dense<<<dim3(64, 4), 256, 0, stream>>>(x, Win, net);

  for (int t = 0; t < TT; t++) {
    float* st1 = stats;
    float* st2 = stats + 4096;
    hipMemsetAsync(stats, 0, 8192 * sizeof(float), stream);

    const float* cg = (t == 0) ? affgI : affg2;
    const float* cb = (t == 0) ? affbI : affb2;

    k_prep<<<dim3(10, 4, 8), 256, 0, stream>>>(Wq, Wk, Wv, Wd, wph, wpl, t);
    k_mm_qkv<<<dim3(64, 8), 256, 0, stream>>>(net, cg, cb, wph, wpl,
                                              qph, qpl, kph, kpl, vth, vtl);
    k_attn<<<dim3(32, 4, 8), 256, 0, stream>>>(qph, qpl, kph, kpl, vth, vtl,
                                               net, cg, cb, st1, tmp);
    k_affine<<<dim3(8), 256, 0, stream>>>(st1, g1, b1, t, affg1, affb1);
    k_mm_dense<<<dim3(64, 8), 256, 0, stream>>>(tmp, affg1, affb1, wph, wpl,
                                                net, st2);
    if (t < TT - 1)
      k_affine<<<dim3(8), 256, 0, stream>>>(st2, g2, b2, t, affg2, affb2);
    else
      k_bnapply<<<dim3(64, 8), 256, 0, stream>>>(net, nullptr, st2, g2, b2,
                                                 out, t, 0, 1);
  }
}

// Round 9
// 872.559 us; speedup vs baseline: 1.1864x; 1.1864x over previous
//
#include <hip/hip_runtime.h>
#include <hip/hip_bf16.h>
#include <math.h>

// Problem constants
#define BB   4
#define SS   1024
#define VV   256
#define KDIM 64
#define HH   8
#define TT   4
#define EPSV 1e-3f
#define SCL  0.125f        // KD^-0.5
#define INV2048 4.8828125e-4f

typedef float f4 __attribute__((ext_vector_type(4)));
typedef short bf8 __attribute__((ext_vector_type(8)));       // 8 bf16
typedef _Float16 h8 __attribute__((ext_vector_type(8)));     // 8 f16
typedef _Float16 h4 __attribute__((ext_vector_type(4)));

#define LDP 68   // fp32 GEMM LDS stride (floats)
#define LHS 68   // split-f16 GEMM LDS stride (halves; 34 dwords -> 2-way, free)

__device__ __forceinline__ short f2bf(float x) {
  __hip_bfloat16 h = __float2bfloat16(x);   // RNE
  return *reinterpret_cast<short*>(&h);
}
__device__ __forceinline__ float bf2f(short h) {
  union { unsigned u; float f; } cv;
  cv.u = ((unsigned)(unsigned short)h) << 16;
  return cv.f;
}

// XCD-aware bijective swizzle for 512-block 1D grids (8 XCDs, 64 each):
// XCD x (blocks with L%8==x under round-robin dispatch) gets the
// contiguous logical chunk [64x, 64x+64).
__device__ __forceinline__ int xcd_swz512(int L) {
  return (L & 7) * 64 + (L >> 3);
}

// ---------------------------------------------------------------------------
// identity affine init (t=0 consumers)
// ---------------------------------------------------------------------------
__global__ __launch_bounds__(256) void k_init(float* __restrict__ g, float* __restrict__ b)
{
  int i = blockIdx.x * 256 + threadIdx.x;
  g[i] = 1.f; b[i] = 0.f;
}

// ---------------------------------------------------------------------------
// stats + gamma/beta -> per-column affine (g', b'):  BN(x) = x*g' + b'
// ---------------------------------------------------------------------------
__global__ __launch_bounds__(256) void k_affine(
    const float* __restrict__ st, const float* __restrict__ gamma,
    const float* __restrict__ beta, int t,
    float* __restrict__ ag, float* __restrict__ ab)
{
  int h = blockIdx.x, c = threadIdx.x;
  float s  = st[(h * 256 + c) * 2];
  float s2 = st[(h * 256 + c) * 2 + 1];
  float mean = s * (1.f / 4096.f);
  float var  = s2 * (1.f / 4096.f) - mean * mean;
  float g = gamma[(h * TT + t) * 256 + c] * rsqrtf(var + EPSV);
  ag[h * 256 + c] = g;
  ab[h * 256 + c] = beta[(h * TT + t) * 256 + c] - mean * g;
}

// ---------------------------------------------------------------------------
// fp32 GEMM core (R4, proven) — used only by k_in_dense (1 dispatch).
// ---------------------------------------------------------------------------
__device__ __forceinline__ void gemm_core(
    const float* __restrict__ A, const float* __restrict__ Bm, int ldb,
    float acc[4][4], float (*As)[LDP], float (*Bs)[LDP])
{
  const int tid = threadIdx.x;
  const int tx = tid & 15, ty = tid >> 4;
#pragma unroll
  for (int i = 0; i < 4; i++)
#pragma unroll
    for (int j = 0; j < 4; j++) acc[i][j] = 0.f;

  for (int k0 = 0; k0 < 256; k0 += 16) {
#pragma unroll
    for (int l = 0; l < 4; l++) {
      int e = tid + l * 256;
      int r = e >> 4, kk = e & 15;
      As[kk][r] = A[r * 256 + k0 + kk];
      int rb = e >> 6, nn = e & 63;
      Bs[rb][nn] = Bm[(k0 + rb) * ldb + nn];
    }
    __syncthreads();
#pragma unroll
    for (int kk = 0; kk < 16; kk++) {
      f4 av = *(const f4*)&As[kk][ty * 4];
      f4 bv = *(const f4*)&Bs[kk][tx * 4];
#pragma unroll
      for (int i = 0; i < 4; i++)
#pragma unroll
        for (int j = 0; j < 4; j++)
          acc[i][j] += av[i] * bv[j];
    }
    __syncthreads();
  }
}

// ---------------------------------------------------------------------------
// net0 = x @ W_in, broadcast into all H head slots (R4 verbatim)
// ---------------------------------------------------------------------------
__global__ __launch_bounds__(256) void k_in_dense(
    const float* __restrict__ x, const float* __restrict__ Win,
    float* __restrict__ net)
{
  __shared__ __align__(16) float As[16][LDP];
  __shared__ __align__(16) float Bs[16][LDP];
  const int mt = blockIdx.x, nt = blockIdx.y;
  float acc[4][4];
  gemm_core(x + mt * 64 * 256, Win + nt * 64, 256, acc, As, Bs);
  const int tx = threadIdx.x & 15, ty = threadIdx.x >> 4;
#pragma unroll
  for (int i = 0; i < 4; i++) {
    f4 v;
#pragma unroll
    for (int j = 0; j < 4; j++) v[j] = acc[i][j];
    int row = mt * 64 + ty * 4 + i;
    int col = nt * 64 + tx * 4;
    for (int h = 0; h < HH; h++)
      *(f4*)&net[(size_t)h * 1048576 + row * 256 + col] = v;
  }
}

// ---------------------------------------------------------------------------
// Weight prep (per t): transpose + split into f16 hi/lo, layout [n][k(256)].
// ---------------------------------------------------------------------------
__global__ __launch_bounds__(256) void k_prep(
    const float* __restrict__ Wq, const float* __restrict__ Wk,
    const float* __restrict__ Wv, const float* __restrict__ Wd,
    _Float16* __restrict__ oh, _Float16* __restrict__ ol, int t)
{
  __shared__ __align__(16) _Float16 Th[64][LHS];
  __shared__ __align__(16) _Float16 Tl[64][LHS];
  const int xb = blockIdx.x, kb = blockIdx.y, h = blockIdx.z;
  const int tid = threadIdx.x;
  const float* src; int N, nb; size_t dbase;
  if (xb == 0)      { src = Wq; N = 64;  nb = 0;      dbase = (size_t)h * 16384; }
  else if (xb == 1) { src = Wk; N = 64;  nb = 0;      dbase = 131072 + (size_t)h * 16384; }
  else if (xb < 6)  { src = Wv; N = 256; nb = xb - 2; dbase = 262144 + (size_t)h * 65536; }
  else              { src = Wd; N = 256; nb = xb - 6; dbase = 786432 + (size_t)h * 65536; }
  src += (size_t)(h * TT + t) * 256 * N;
#pragma unroll
  for (int i = 0; i < 4; i++) {
    int fi = tid + i * 256;
    int r = fi >> 4, c4 = fi & 15;
    f4 w = *(const f4*)&src[(size_t)(kb * 64 + r) * N + nb * 64 + c4 * 4];
    h4 hv, lv;
#pragma unroll
    for (int j = 0; j < 4; j++) {
      _Float16 hi = (_Float16)w[j];
      hv[j] = hi;
      lv[j] = (_Float16)((w[j] - (float)hi) * 2048.f);
    }
    *(h4*)&Th[r][c4 * 4] = hv;
    *(h4*)&Tl[r][c4 * 4] = lv;
  }
  __syncthreads();
#pragma unroll
  for (int i = 0; i < 4; i++) {
    int fo = tid + i * 256;
    int nr = fo >> 4, k4 = fo & 15;
    h4 hv, lv;
#pragma unroll
    for (int j = 0; j < 4; j++) { hv[j] = Th[k4 * 4 + j][nr]; lv[j] = Tl[k4 * 4 + j][nr]; }
    size_t d = dbase + (size_t)(nb * 64 + nr) * 256 + kb * 64 + k4 * 4;
    *(h4*)&oh[d] = hv;
    *(h4*)&ol[d] = lv;
  }
}

// ---------------------------------------------------------------------------
// A-tile staging with on-the-fly per-column affine (BN fold):
// issue loads to regs (+fma), split+write to LDS later.
// ---------------------------------------------------------------------------
__device__ __forceinline__ void stage_issue_aff(
    const float* __restrict__ A, const float* __restrict__ ag,
    const float* __restrict__ ab, int kc, int tid, f4 w[4])
{
#pragma unroll
  for (int i = 0; i < 4; i++) {
    int fi = tid + i * 256;
    int r = fi >> 4, c4 = fi & 15;
    f4 raw = *(const f4*)&A[(size_t)r * 256 + kc * 64 + c4 * 4];
    f4 g = *(const f4*)&ag[kc * 64 + c4 * 4];
    f4 b = *(const f4*)&ab[kc * 64 + c4 * 4];
#pragma unroll
    for (int j = 0; j < 4; j++) w[i][j] = fmaf(raw[j], g[j], b[j]);
  }
}
__device__ __forceinline__ void stage_write(
    const f4 w[4], int tid, _Float16 (*Ah)[LHS], _Float16 (*Al)[LHS])
{
#pragma unroll
  for (int i = 0; i < 4; i++) {
    int fi = tid + i * 256;
    int r = fi >> 4, c4 = fi & 15;
    h4 hv, lv;
#pragma unroll
    for (int j = 0; j < 4; j++) {
      _Float16 hi = (_Float16)w[i][j];
      hv[j] = hi;
      lv[j] = (_Float16)((w[i][j] - (float)hi) * 2048.f);
    }
    *(h4*)&Ah[r][c4 * 4] = hv;
    *(h4*)&Al[r][c4 * 4] = lv;
  }
}

// ---------------------------------------------------------------------------
// QKV GEMM (merged): A = affine(net) staged once per half, dbuf + prefetch.
// grid (512): XCD-swizzled so XCD x owns h == x (weights L2-resident).
// ---------------------------------------------------------------------------
__global__ __launch_bounds__(256) void k_mm_qkv(
    const float* __restrict__ net,
    const float* __restrict__ affg, const float* __restrict__ affb,
    const _Float16* __restrict__ wph, const _Float16* __restrict__ wpl,
    _Float16* __restrict__ qph, _Float16* __restrict__ qpl,
    _Float16* __restrict__ kph, _Float16* __restrict__ kpl,
    short* __restrict__ vth, short* __restrict__ vtl)
{
  __shared__ __align__(16) _Float16 Ah[2][64][LHS];
  __shared__ __align__(16) _Float16 Al[2][64][LHS];
  const int logical = xcd_swz512(blockIdx.x);
  const int mt = logical & 63, h = logical >> 6;
  const int tid = threadIdx.x, wv = tid >> 6, lane = tid & 63;
  const int ln = lane & 15, quad = lane >> 4;
  const float* A = net + (size_t)h * 1048576 + (size_t)mt * 64 * 256;
  const float* ag = affg + h * 256;
  const float* ab = affb + h * 256;

  for (int half = 0; half < 2; half++) {
    size_t bb[3];
#pragma unroll
    for (int j = 0; j < 3; j++) {
      int nt = half * 3 + j;
      if (nt == 0)      bb[j] = (size_t)h * 16384;
      else if (nt == 1) bb[j] = 131072 + (size_t)h * 16384;
      else              bb[j] = 262144 + (size_t)h * 65536 + (size_t)(nt - 2) * 16384;
      bb[j] += (size_t)(wv * 16 + ln) * 256;
    }

    f4 mn[3][4], cr[3][4];
#pragma unroll
    for (int j = 0; j < 3; j++)
#pragma unroll
      for (int mf = 0; mf < 4; mf++) {
        mn[j][mf] = (f4){0.f, 0.f, 0.f, 0.f};
        cr[j][mf] = (f4){0.f, 0.f, 0.f, 0.f};
      }

    f4 w[4];
    stage_issue_aff(A, ag, ab, 0, tid, w);
    stage_write(w, tid, Ah[0], Al[0]);
    __syncthreads();

    for (int kc = 0; kc < 4; kc++) {
      const int buf = kc & 1;
      if (kc < 3) stage_issue_aff(A, ag, ab, kc + 1, tid, w);
#pragma unroll
      for (int j = 0; j < 3; j++) {
        const _Float16* bh = wph + bb[j] + kc * 64;
        const _Float16* bl = wpl + bb[j] + kc * 64;
        h8 bh0 = *(const h8*)&bh[quad * 8];
        h8 bh1 = *(const h8*)&bh[32 + quad * 8];
        h8 bl0 = *(const h8*)&bl[quad * 8];
        h8 bl1 = *(const h8*)&bl[32 + quad * 8];
#pragma unroll
        for (int mf = 0; mf < 4; mf++) {
          h8 ah0 = *(const h8*)&Ah[buf][mf * 16 + ln][quad * 8];
          h8 ah1 = *(const h8*)&Ah[buf][mf * 16 + ln][32 + quad * 8];
          h8 al0 = *(const h8*)&Al[buf][mf * 16 + ln][quad * 8];
          h8 al1 = *(const h8*)&Al[buf][mf * 16 + ln][32 + quad * 8];
          mn[j][mf] = __builtin_amdgcn_mfma_f32_16x16x32_f16(ah0, bh0, mn[j][mf], 0, 0, 0);
          mn[j][mf] = __builtin_amdgcn_mfma_f32_16x16x32_f16(ah1, bh1, mn[j][mf], 0, 0, 0);
          cr[j][mf] = __builtin_amdgcn_mfma_f32_16x16x32_f16(ah0, bl0, cr[j][mf], 0, 0, 0);
          cr[j][mf] = __builtin_amdgcn_mfma_f32_16x16x32_f16(ah1, bl1, cr[j][mf], 0, 0, 0);
          cr[j][mf] = __builtin_amdgcn_mfma_f32_16x16x32_f16(al0, bh0, cr[j][mf], 0, 0, 0);
          cr[j][mf] = __builtin_amdgcn_mfma_f32_16x16x32_f16(al1, bh1, cr[j][mf], 0, 0, 0);
        }
      }
      if (kc < 3) stage_write(w, tid, Ah[buf ^ 1], Al[buf ^ 1]);
      __syncthreads();
    }

#pragma unroll
    for (int j = 0; j < 3; j++) {
      int nt = half * 3 + j;
      if (nt <= 1) {
        _Float16* dh = (nt == 0) ? qph : kph;
        _Float16* dl = (nt == 0) ? qpl : kpl;
        int col = wv * 16 + ln;
#pragma unroll
        for (int mf = 0; mf < 4; mf++)
#pragma unroll
          for (int r = 0; r < 4; r++) {
            int row = mt * 64 + mf * 16 + quad * 4 + r;
            int b_ = row >> 10, sI = row & 1023;
            float v = mn[j][mf][r] + cr[j][mf][r] * INV2048;
            _Float16 hi = (_Float16)v;
            size_t idx = ((size_t)(h * 4 + b_) * 1024 + sI) * 64 + col;
            dh[idx] = hi;
            dl[idx] = (_Float16)((v - (float)hi) * 2048.f);
          }
      } else {
        int c = (nt - 2) * 64 + wv * 16 + ln;
#pragma unroll
        for (int mf = 0; mf < 4; mf++)
#pragma unroll
          for (int r = 0; r < 4; r++) {
            int row = mt * 64 + mf * 16 + quad * 4 + r;
            int b_ = row >> 10, sI = row & 1023;
            float v = mn[j][mf][r] + cr[j][mf][r] * INV2048;
            short hi = f2bf(v);
            size_t idx = ((size_t)(h * 4 + b_) * 256 + c) * 1024 + sI;
            vth[idx] = hi;
            vtl[idx] = f2bf(v - bf2f(hi));
          }
      }
    }
  }
}

// ---------------------------------------------------------------------------
// Dense GEMM (merged) + fused BN1-apply + residual + BN2-stats.
// grid (512): XCD-swizzled so XCD x owns h == x.
// ---------------------------------------------------------------------------
__global__ __launch_bounds__(256) void k_mm_dense(
    const float* __restrict__ buf1,
    const float* __restrict__ affg, const float* __restrict__ affb,
    const _Float16* __restrict__ wph, const _Float16* __restrict__ wpl,
    float* __restrict__ buf2, float* __restrict__ st)
{
  __shared__ __align__(16) _Float16 Ah[2][64][LHS];
  __shared__ __align__(16) _Float16 Al[2][64][LHS];
  const int logical = xcd_swz512(blockIdx.x);
  const int mt = logical & 63, h = logical >> 6;
  const int tid = threadIdx.x, wv = tid >> 6, lane = tid & 63;
  const int ln = lane & 15, quad = lane >> 4;
  const float* a1 = buf1 + (size_t)h * 1048576;
  float* o2 = buf2 + (size_t)h * 1048576;
  const float* A = a1 + (size_t)mt * 64 * 256;
  const float* ag = affg + h * 256;
  const float* ab = affb + h * 256;

  for (int half = 0; half < 2; half++) {
    size_t bb[2];
#pragma unroll
    for (int j = 0; j < 2; j++) {
      int nt = half * 2 + j;
      bb[j] = 786432 + (size_t)h * 65536 + (size_t)nt * 16384
            + (size_t)(wv * 16 + ln) * 256;
    }

    f4 mn[2][4], cr[2][4];
#pragma unroll
    for (int j = 0; j < 2; j++)
#pragma unroll
      for (int mf = 0; mf < 4; mf++) {
        mn[j][mf] = (f4){0.f, 0.f, 0.f, 0.f};
        cr[j][mf] = (f4){0.f, 0.f, 0.f, 0.f};
      }

    f4 w[4];
    stage_issue_aff(A, ag, ab, 0, tid, w);
    stage_write(w, tid, Ah[0], Al[0]);
    __syncthreads();

    for (int kc = 0; kc < 4; kc++) {
      const int buf = kc & 1;
      if (kc < 3) stage_issue_aff(A, ag, ab, kc + 1, tid, w);
#pragma unroll
      for (int j = 0; j < 2; j++) {
        const _Float16* bh = wph + bb[j] + kc * 64;
        const _Float16* bl = wpl + bb[j] + kc * 64;
        h8 bh0 = *(const h8*)&bh[quad * 8];
        h8 bh1 = *(const h8*)&bh[32 + quad * 8];
        h8 bl0 = *(const h8*)&bl[quad * 8];
        h8 bl1 = *(const h8*)&bl[32 + quad * 8];
#pragma unroll
        for (int mf = 0; mf < 4; mf++) {
          h8 ah0 = *(const h8*)&Ah[buf][mf * 16 + ln][quad * 8];
          h8 ah1 = *(const h8*)&Ah[buf][mf * 16 + ln][32 + quad * 8];
          h8 al0 = *(const h8*)&Al[buf][mf * 16 + ln][quad * 8];
          h8 al1 = *(const h8*)&Al[buf][mf * 16 + ln][32 + quad * 8];
          mn[j][mf] = __builtin_amdgcn_mfma_f32_16x16x32_f16(ah0, bh0, mn[j][mf], 0, 0, 0);
          mn[j][mf] = __builtin_amdgcn_mfma_f32_16x16x32_f16(ah1, bh1, mn[j][mf], 0, 0, 0);
          cr[j][mf] = __builtin_amdgcn_mfma_f32_16x16x32_f16(ah0, bl0, cr[j][mf], 0, 0, 0);
          cr[j][mf] = __builtin_amdgcn_mfma_f32_16x16x32_f16(ah1, bl1, cr[j][mf], 0, 0, 0);
          cr[j][mf] = __builtin_amdgcn_mfma_f32_16x16x32_f16(al0, bh0, cr[j][mf], 0, 0, 0);
          cr[j][mf] = __builtin_amdgcn_mfma_f32_16x16x32_f16(al1, bh1, cr[j][mf], 0, 0, 0);
        }
      }
      if (kc < 3) stage_write(w, tid, Ah[buf ^ 1], Al[buf ^ 1]);
      __syncthreads();
    }

#pragma unroll
    for (int j = 0; j < 2; j++) {
      int nt = half * 2 + j;
      int col = nt * 64 + wv * 16 + ln;
      float gc = ag[col], bc = ab[col];
      float s1 = 0.f, s2 = 0.f;
#pragma unroll
      for (int mf = 0; mf < 4; mf++)
#pragma unroll
        for (int r = 0; r < 4; r++) {
          int row = mt * 64 + mf * 16 + quad * 4 + r;
          size_t idx = (size_t)row * 256 + col;
          float v = mn[j][mf][r] + cr[j][mf][r] * INV2048;
          float yv = fmaf(a1[idx], gc, bc) + fmaxf(v, 0.f);
          o2[idx] = yv;
          s1 += yv; s2 += yv * yv;
        }
      s1 += __shfl_xor(s1, 16, 64); s1 += __shfl_xor(s1, 32, 64);
      s2 += __shfl_xor(s2, 16, 64); s2 += __shfl_xor(s2, 32, 64);
      if (quad == 0) {
        atomicAdd(&st[(h * 256 + col) * 2],     s1);
        atomicAdd(&st[(h * 256 + col) * 2 + 1], s2);
      }
    }
  }
}

// ---------------------------------------------------------------------------
// Flash attention v10 = v8 (proven 102 us) + XCD swizzle: XCD x owns
// hb in {4x..4x+3} (all 16 qt each) -> K/V L2-resident per XCD.
// K/P LDS overlay (48 KB), 6 barriers/kt, defer-max, fused BN1 epilogue.
// grid (512 1D): logical = swz(L); qt = logical&15, hb = logical>>4.
// ---------------------------------------------------------------------------
__global__ __launch_bounds__(256, 2) void k_attn(
    const _Float16* __restrict__ qfh, const _Float16* __restrict__ qfl,
    const _Float16* __restrict__ kfh, const _Float16* __restrict__ kfl,
    const short* __restrict__ vth, const short* __restrict__ vtl,
    const float* __restrict__ resid,
    const float* __restrict__ affg, const float* __restrict__ affb,
    float* __restrict__ st, float* __restrict__ obuf)
{
  // AB0: Kh <-> Ph ; AB1: Kl <-> Pl  (8 KB each, swizzled [64][64])
  __shared__ __align__(16) short AB0[64][64];     // 8 KB
  __shared__ __align__(16) short AB1[64][64];     // 8 KB
  __shared__ __align__(16) short VhS[2][64][64];  // 16 KB
  __shared__ __align__(16) short VlS[2][64][64];  // 16 KB  => 48 KB total

  const int logical = xcd_swz512(blockIdx.x);
  const int qt = logical & 15, hb = logical >> 4;
  const int b = hb & 3, h = hb >> 2;
  const int tid = threadIdx.x;
  const int wv = tid >> 6, lane = tid & 63, ln = lane & 15, quad = lane >> 4;
  const int swz = (ln & 7) << 3;

  const _Float16* qgh = qfh + ((size_t)hb * 1024 + qt * 64 + wv * 16 + ln) * 64;
  const _Float16* qgl = qfl + ((size_t)hb * 1024 + qt * 64 + wv * 16 + ln) * 64;
  h8 aqh0 = *(const h8*)&qgh[quad * 8];
  h8 aqh1 = *(const h8*)&qgh[32 + quad * 8];
  h8 aql0 = *(const h8*)&qgl[quad * 8];
  h8 aql1 = *(const h8*)&qgl[32 + quad * 8];

  const _Float16* kgh = kfh + (size_t)hb * 65536;   // [1024 s][64 kd]
  const _Float16* kgl = kfl + (size_t)hb * 65536;
  const short* vhg = vth + (size_t)hb * 262144;     // [256 vcol][1024 s]
  const short* vlg = vtl + (size_t)hb * 262144;

  float m[4] = {-1e30f, -1e30f, -1e30f, -1e30f};
  float l[4] = {0.f, 0.f, 0.f, 0.f};
  f4 O[16];
#pragma unroll
  for (int nt = 0; nt < 16; nt++) O[nt] = (f4){0.f, 0.f, 0.f, 0.f};

  // ---- prologue: stage K(0) into AB and V(kt=0, c4=0) into buf 0 ----
#pragma unroll
  for (int i = 0; i < 2; i++) {
    int e = tid + i * 256;
    int r = e >> 3, c8 = e & 7;
    int cc = (c8 * 8) ^ ((r & 7) << 3);
    *(h8*)&AB0[r][cc] = *(const h8*)&kgh[(size_t)r * 64 + c8 * 8];
    *(h8*)&AB1[r][cc] = *(const h8*)&kgl[(size_t)r * 64 + c8 * 8];
  }
#pragma unroll
  for (int i = 0; i < 2; i++) {
    int e = tid + i * 256;
    int vc = e >> 3, fc = e & 7;
    int cc = (fc * 8) ^ ((vc & 7) << 3);
    size_t g = (size_t)vc * 1024 + fc * 8;
    *(bf8*)&VhS[0][vc][cc] = *(const bf8*)&vhg[g];
    *(bf8*)&VlS[0][vc][cc] = *(const bf8*)&vlg[g];
  }
  __syncthreads();

  for (int kt = 0; kt < 16; kt++) {
    // ---- QK^T: K frags from AB (swizzled) ----
    f4 sv[4];
#pragma unroll
    for (int nf = 0; nf < 4; nf++) {
      int row = nf * 16 + ln;
      h8 bkh0 = *(const h8*)&AB0[row][(quad * 8) ^ swz];
      h8 bkh1 = *(const h8*)&AB0[row][(32 + quad * 8) ^ swz];
      h8 bkl0 = *(const h8*)&AB1[row][(quad * 8) ^ swz];
      h8 bkl1 = *(const h8*)&AB1[row][(32 + quad * 8) ^ swz];
      f4 mn = (f4){0.f, 0.f, 0.f, 0.f};
      f4 cr = (f4){0.f, 0.f, 0.f, 0.f};
      mn = __builtin_amdgcn_mfma_f32_16x16x32_f16(aqh0, bkh0, mn, 0, 0, 0);
      mn = __builtin_amdgcn_mfma_f32_16x16x32_f16(aqh1, bkh1, mn, 0, 0, 0);
      cr = __builtin_amdgcn_mfma_f32_16x16x32_f16(aqh0, bkl0, cr, 0, 0, 0);
      cr = __builtin_amdgcn_mfma_f32_16x16x32_f16(aqh1, bkl1, cr, 0, 0, 0);
      cr = __builtin_amdgcn_mfma_f32_16x16x32_f16(aql0, bkh0, cr, 0, 0, 0);
      cr = __builtin_amdgcn_mfma_f32_16x16x32_f16(aql1, bkh1, cr, 0, 0, 0);
#pragma unroll
      for (int r = 0; r < 4; r++) sv[nf][r] = (mn[r] + cr[r] * INV2048) * SCL;
    }

    // barrier: all waves done READING K before P overwrites the region.
    __syncthreads();   // B1

    // ---- online softmax with defer-max (T13, THR=8) ----
    float mloc[4];
#pragma unroll
    for (int r = 0; r < 4; r++) {
      float v0 = fmaxf(fmaxf(sv[0][r], sv[1][r]), fmaxf(sv[2][r], sv[3][r]));
#pragma unroll
      for (int d = 1; d < 16; d <<= 1)
        v0 = fmaxf(v0, __shfl_xor(v0, d, 64));
      mloc[r] = v0;
    }
    float growth = fmaxf(fmaxf(mloc[0] - m[0], mloc[1] - m[1]),
                         fmaxf(mloc[2] - m[2], mloc[3] - m[3]));
    if (__any(growth > 8.f)) {
      float alpha[4];
#pragma unroll
      for (int r = 0; r < 4; r++) {
        float mnew = fmaxf(m[r], mloc[r]);
        alpha[r] = __expf(m[r] - mnew);
        m[r] = mnew;
        l[r] *= alpha[r];
      }
#pragma unroll
      for (int nt = 0; nt < 16; nt++)
#pragma unroll
        for (int i = 0; i < 4; i++) O[nt][i] *= alpha[i];
    }
#pragma unroll
    for (int r = 0; r < 4; r++) {
      float ls = 0.f;
#pragma unroll
      for (int nf = 0; nf < 4; nf++) {
        float p = __expf(sv[nf][r] - m[r]);
        sv[nf][r] = p;
        ls += p;
      }
#pragma unroll
      for (int d = 1; d < 16; d <<= 1) ls += __shfl_xor(ls, d, 64);
      l[r] += ls;
    }

    // ---- publish P into AB (swizzled; own rows) ----
#pragma unroll
    for (int nf = 0; nf < 4; nf++)
#pragma unroll
      for (int r = 0; r < 4; r++) {
        int row = wv * 16 + quad * 4 + r;
        int c = (nf * 16 + ln) ^ ((row & 7) << 3);
        float p = sv[nf][r];
        short hi = f2bf(p);
        AB0[row][c] = hi;
        AB1[row][c] = f2bf(p - bf2f(hi));
      }
    __syncthreads();   // B2: P ready

    // ---- P fragments (own 16 rows); AB dead for P after this ----
    bf8 ph0 = *(const bf8*)&AB0[wv * 16 + ln][(quad * 8) ^ swz];
    bf8 ph1 = *(const bf8*)&AB0[wv * 16 + ln][(32 + quad * 8) ^ swz];
    bf8 pl0 = *(const bf8*)&AB1[wv * 16 + ln][(quad * 8) ^ swz];
    bf8 pl1 = *(const bf8*)&AB1[wv * 16 + ln][(32 + quad * 8) ^ swz];

    for (int c4 = 0; c4 < 4; c4++) {
      const int buf = c4 & 1;
      const bool haveNext = (c4 < 3) || (kt < 15);
      const int nkt = (c4 < 3) ? kt : kt + 1;
      const int nc4 = (c4 < 3) ? c4 + 1 : 0;
      const bool pfK = (c4 == 3) && (kt < 15);

      const int vc0 = tid >> 3, fc0 = tid & 7;
      const int vc1 = vc0 + 32;
      bf8 fvh0, fvh1, fvl0, fvl1;
      if (haveNext) {
        size_t g0 = (size_t)(nc4 * 64 + vc0) * 1024 + nkt * 64 + fc0 * 8;
        size_t g1 = (size_t)(nc4 * 64 + vc1) * 1024 + nkt * 64 + fc0 * 8;
        fvh0 = *(const bf8*)&vhg[g0]; fvl0 = *(const bf8*)&vlg[g0];
        fvh1 = *(const bf8*)&vhg[g1]; fvl1 = *(const bf8*)&vlg[g1];
      }
      h8 fkh0, fkh1, fkl0, fkl1;
      if (pfK) {
        size_t g0 = (size_t)((kt + 1) * 64 + vc0) * 64 + fc0 * 8;
        size_t g1 = (size_t)((kt + 1) * 64 + vc1) * 64 + fc0 * 8;
        fkh0 = *(const h8*)&kgh[g0]; fkl0 = *(const h8*)&kgl[g0];
        fkh1 = *(const h8*)&kgh[g1]; fkl1 = *(const h8*)&kgl[g1];
      }

#pragma unroll
      for (int n2 = 0; n2 < 4; n2++) {
        int nt = c4 * 4 + n2;
        int vrow = n2 * 16 + ln;
        bf8 vh0 = *(const bf8*)&VhS[buf][vrow][(quad * 8) ^ swz];
        bf8 vh1 = *(const bf8*)&VhS[buf][vrow][(32 + quad * 8) ^ swz];
        bf8 vl0 = *(const bf8*)&VlS[buf][vrow][(quad * 8) ^ swz];
        bf8 vl1 = *(const bf8*)&VlS[buf][vrow][(32 + quad * 8) ^ swz];
        O[nt] = __builtin_amdgcn_mfma_f32_16x16x32_bf16(ph0, vh0, O[nt], 0, 0, 0);
        O[nt] = __builtin_amdgcn_mfma_f32_16x16x32_bf16(ph1, vh1, O[nt], 0, 0, 0);
        O[nt] = __builtin_amdgcn_mfma_f32_16x16x32_bf16(ph0, vl0, O[nt], 0, 0, 0);
        O[nt] = __builtin_amdgcn_mfma_f32_16x16x32_bf16(ph1, vl1, O[nt], 0, 0, 0);
        O[nt] = __builtin_amdgcn_mfma_f32_16x16x32_bf16(pl0, vh0, O[nt], 0, 0, 0);
        O[nt] = __builtin_amdgcn_mfma_f32_16x16x32_bf16(pl1, vh1, O[nt], 0, 0, 0);
      }

      if (haveNext) {
        int cc0 = (fc0 * 8) ^ ((vc0 & 7) << 3);
        int cc1 = (fc0 * 8) ^ ((vc1 & 7) << 3);
        *(bf8*)&VhS[buf ^ 1][vc0][cc0] = fvh0;
        *(bf8*)&VlS[buf ^ 1][vc0][cc0] = fvl0;
        *(bf8*)&VhS[buf ^ 1][vc1][cc1] = fvh1;
        *(bf8*)&VlS[buf ^ 1][vc1][cc1] = fvl1;
      }
      if (pfK) {
        // safe: every wave's P-frag reads happened before B3[0]; we are
        // past B3[2], so AB is dead for P and free for K(kt+1).
        int cc0 = (fc0 * 8) ^ ((vc0 & 7) << 3);
        int cc1 = (fc0 * 8) ^ ((vc1 & 7) << 3);
        *(h8*)&AB0[vc0][cc0] = fkh0;
        *(h8*)&AB1[vc0][cc0] = fkl0;
        *(h8*)&AB0[vc1][cc1] = fkh1;
        *(h8*)&AB1[vc1][cc1] = fkl1;
      }
      __syncthreads();   // B3[c4]
    }
  }

  // ---- fused epilogue: y1 = affine(resid) + O/l -> buf1; BN1 stats ----
  const float* rg = affg + h * 256;
  const float* rb = affb + h * 256;
  const float* rs = resid + (size_t)h * 1048576
                  + (size_t)(b * 1024 + qt * 64 + wv * 16 + quad * 4) * 256;
  float* ds = obuf + (size_t)h * 1048576
            + (size_t)(b * 1024 + qt * 64 + wv * 16 + quad * 4) * 256;
  float linv[4];
#pragma unroll
  for (int r = 0; r < 4; r++) linv[r] = 1.f / l[r];

  float* S1 = (float*)&AB0[0][0];   // AB free after the loop
  float* S2 = (float*)&AB1[0][0];
#pragma unroll
  for (int nt = 0; nt < 16; nt++) {
    int c = nt * 16 + ln;
    float gc = rg[c], bc = rb[c];
    float s1 = 0.f, s2 = 0.f;
#pragma unroll
    for (int r = 0; r < 4; r++) {
      float yv = fmaf(rs[r * 256 + c], gc, bc) + O[nt][r] * linv[r];
      ds[r * 256 + c] = yv;
      s1 += yv; s2 += yv * yv;
    }
    s1 += __shfl_xor(s1, 16, 64); s1 += __shfl_xor(s1, 32, 64);
    s2 += __shfl_xor(s2, 16, 64); s2 += __shfl_xor(s2, 32, 64);
    if (quad == 0) { S1[wv * 256 + c] = s1; S2[wv * 256 + c] = s2; }
  }
  __syncthreads();
  if (tid < 256) {
    float a1 = S1[tid] + S1[256 + tid] + S1[512 + tid] + S1[768 + tid];
    float a2 = S2[tid] + S2[256 + tid] + S2[512 + tid] + S2[768 + tid];
    atomicAdd(&st[(h * 256 + tid) * 2],     a1);
    atomicAdd(&st[(h * 256 + tid) * 2 + 1], a2);
  }
}

// ---------------------------------------------------------------------------
// BN apply (final t only: transposed output)
// ---------------------------------------------------------------------------
__global__ __launch_bounds__(256) void k_bnapply(
    const float* __restrict__ a, const float* __restrict__ b,
    const float* __restrict__ stats,
    const float* __restrict__ gamma, const float* __restrict__ beta,
    float* __restrict__ dst, int t, int addB, int transposed)
{
  const int h = blockIdx.y, r0 = blockIdx.x * 64, c = threadIdx.x;
  float s  = stats[(h * 256 + c) * 2];
  float s2 = stats[(h * 256 + c) * 2 + 1];
  float mean = s * (1.f / 4096.f);
  float var  = s2 * (1.f / 4096.f) - mean * mean;
  float inv  = rsqrtf(var + EPSV);
  float g  = gamma[(h * TT + t) * 256 + c] * inv;
  float bt = beta[(h * TT + t) * 256 + c];
  const float* pa = a + (size_t)h * 1048576 + r0 * 256 + c;
  const float* pb = addB ? (b + (size_t)h * 1048576 + r0 * 256 + c) : nullptr;
  for (int r = 0; r < 64; r++) {
    float y = pa[r * 256];
    if (addB) y += pb[r * 256];
    float o = (y - mean) * g + bt;
    int rg = r0 + r;
    if (transposed) dst[((size_t)rg * HH + h) * 256 + c] = o;
    else            dst[(size_t)h * 1048576 + rg * 256 + c] = o;
  }
}

// ---------------------------------------------------------------------------
extern "C" void kernel_launch(void* const* d_in, const int* in_sizes, int n_in,
                              void* d_out, int out_size, void* d_ws, size_t ws_size,
                              hipStream_t stream)
{
  const float* x   = (const float*)d_in[0];
  const float* Win = (const float*)d_in[1];
  const float* Wq  = (const float*)d_in[2];
  const float* Wk  = (const float*)d_in[3];
  const float* Wv  = (const float*)d_in[4];
  const float* Wd  = (const float*)d_in[5];
  const float* g1  = (const float*)d_in[6];
  const float* b1  = (const float*)d_in[7];
  const float* g2  = (const float*)d_in[8];
  const float* b2  = (const float*)d_in[9];
  float* out = (float*)d_out;
  float* ws  = (float*)d_ws;

  float* net   = ws;                       // buf2: pre-BN2 state (or net0)
  float* tmp   = net + 8388608;            // buf1: pre-BN1 state (y1)
  float* stats = tmp + 8388608;            // 2 phases * H*V*2 = 8192 f
  float* affg1 = stats + 8192;             // 2048 f each
  float* affb1 = affg1 + 2048;
  float* affg2 = affb1 + 2048;
  float* affb2 = affg2 + 2048;
  float* affgI = affb2 + 2048;
  float* affbI = affgI + 2048;             // ends at stats+20480 < stats+32768
  _Float16* qph = (_Float16*)(stats + 32768);  // 2,097,152 h
  _Float16* qpl = qph + 2097152;
  _Float16* kph = qpl + 2097152;
  _Float16* kpl = kph + 2097152;
  short* vth   = (short*)(kpl + 2097152);
  short* vtl   = vth + 8388608;
  _Float16* wph = (_Float16*)(vtl + 8388608);
  _Float16* wpl = wph + 1310720;

  k_init<<<dim3(8), 256, 0, stream>>>(affgI, affbI);
  k_in_dense<<<dim3(64, 4), 256, 0, stream>>>(x, Win, net);

  for (int t = 0; t < TT; t++) {
    float* st1 = stats;
    float* st2 = stats + 4096;
    hipMemsetAsync(stats, 0, 8192 * sizeof(float), stream);

    const float* cg = (t == 0) ? affgI : affg2;
    const float* cb = (t == 0) ? affbI : affb2;

    k_prep<<<dim3(10, 4, 8), 256, 0, stream>>>(Wq, Wk, Wv, Wd, wph, wpl, t);
    k_mm_qkv<<<dim3(512), 256, 0, stream>>>(net, cg, cb, wph, wpl,
                                            qph, qpl, kph, kpl, vth, vtl);
    k_attn<<<dim3(512), 256, 0, stream>>>(qph, qpl, kph, kpl, vth, vtl,
                                          net, cg, cb, st1, tmp);
    k_affine<<<dim3(8), 256, 0, stream>>>(st1, g1, b1, t, affg1, affb1);
    k_mm_dense<<<dim3(512), 256, 0, stream>>>(tmp, affg1, affb1, wph, wpl,
                                              net, st2);
    if (t < TT - 1)
      k_affine<<<dim3(8), 256, 0, stream>>>(st2, g2, b2, t, affg2, affb2);
    else
      k_bnapply<<<dim3(64, 8), 256, 0, stream>>>(net, nullptr, st2, g2, b2,
                                                 out, t, 0, 1);
  }
}

// Round 10
// 844.641 us; speedup vs baseline: 1.2256x; 1.0331x over previous
//
#include <hip/hip_runtime.h>
#include <hip/hip_bf16.h>
#include <math.h>

// Problem constants
#define BB   4
#define SS   1024
#define VV   256
#define KDIM 64
#define HH   8
#define TT   4
#define EPSV 1e-3f
#define SCL  0.125f        // KD^-0.5
#define INV2048 4.8828125e-4f

typedef float f4 __attribute__((ext_vector_type(4)));
typedef short bf8 __attribute__((ext_vector_type(8)));       // 8 bf16
typedef _Float16 h8 __attribute__((ext_vector_type(8)));     // 8 f16
typedef _Float16 h4 __attribute__((ext_vector_type(4)));

#define LDP 68   // fp32 GEMM LDS stride (floats)
#define LHS 68   // split-f16 GEMM LDS stride (halves; 34 dwords -> 2-way, free)

__device__ __forceinline__ short f2bf(float x) {
  __hip_bfloat16 h = __float2bfloat16(x);   // RNE
  return *reinterpret_cast<short*>(&h);
}
__device__ __forceinline__ float bf2f(short h) {
  union { unsigned u; float f; } cv;
  cv.u = ((unsigned)(unsigned short)h) << 16;
  return cv.f;
}

// XCD-aware bijective swizzles (8 XCDs; blocks round-robin by L%8).
__device__ __forceinline__ int xcd_swz512(int L)  { return (L & 7) * 64  + (L >> 3); }
__device__ __forceinline__ int xcd_swz1024(int L) { return (L & 7) * 128 + (L >> 3); }

// ---------------------------------------------------------------------------
// identity affine init (t=0 consumers)
// ---------------------------------------------------------------------------
__global__ __launch_bounds__(256) void k_init(float* __restrict__ g, float* __restrict__ b)
{
  int i = blockIdx.x * 256 + threadIdx.x;
  g[i] = 1.f; b[i] = 0.f;
}

// ---------------------------------------------------------------------------
// stats + gamma/beta -> per-column affine (g', b'):  BN(x) = x*g' + b'
// ---------------------------------------------------------------------------
__global__ __launch_bounds__(256) void k_affine(
    const float* __restrict__ st, const float* __restrict__ gamma,
    const float* __restrict__ beta, int t,
    float* __restrict__ ag, float* __restrict__ ab)
{
  int h = blockIdx.x, c = threadIdx.x;
  float s  = st[(h * 256 + c) * 2];
  float s2 = st[(h * 256 + c) * 2 + 1];
  float mean = s * (1.f / 4096.f);
  float var  = s2 * (1.f / 4096.f) - mean * mean;
  float g = gamma[(h * TT + t) * 256 + c] * rsqrtf(var + EPSV);
  ag[h * 256 + c] = g;
  ab[h * 256 + c] = beta[(h * TT + t) * 256 + c] - mean * g;
}

// ---------------------------------------------------------------------------
// fp32 GEMM core (R4, proven) — used only by k_in_dense (1 dispatch).
// ---------------------------------------------------------------------------
__device__ __forceinline__ void gemm_core(
    const float* __restrict__ A, const float* __restrict__ Bm, int ldb,
    float acc[4][4], float (*As)[LDP], float (*Bs)[LDP])
{
  const int tid = threadIdx.x;
  const int tx = tid & 15, ty = tid >> 4;
#pragma unroll
  for (int i = 0; i < 4; i++)
#pragma unroll
    for (int j = 0; j < 4; j++) acc[i][j] = 0.f;

  for (int k0 = 0; k0 < 256; k0 += 16) {
#pragma unroll
    for (int l = 0; l < 4; l++) {
      int e = tid + l * 256;
      int r = e >> 4, kk = e & 15;
      As[kk][r] = A[r * 256 + k0 + kk];
      int rb = e >> 6, nn = e & 63;
      Bs[rb][nn] = Bm[(k0 + rb) * ldb + nn];
    }
    __syncthreads();
#pragma unroll
    for (int kk = 0; kk < 16; kk++) {
      f4 av = *(const f4*)&As[kk][ty * 4];
      f4 bv = *(const f4*)&Bs[kk][tx * 4];
#pragma unroll
      for (int i = 0; i < 4; i++)
#pragma unroll
        for (int j = 0; j < 4; j++)
          acc[i][j] += av[i] * bv[j];
    }
    __syncthreads();
  }
}

// ---------------------------------------------------------------------------
// net0 = x @ W_in, broadcast into all H head slots (R4 verbatim)
// ---------------------------------------------------------------------------
__global__ __launch_bounds__(256) void k_in_dense(
    const float* __restrict__ x, const float* __restrict__ Win,
    float* __restrict__ net)
{
  __shared__ __align__(16) float As[16][LDP];
  __shared__ __align__(16) float Bs[16][LDP];
  const int mt = blockIdx.x, nt = blockIdx.y;
  float acc[4][4];
  gemm_core(x + mt * 64 * 256, Win + nt * 64, 256, acc, As, Bs);
  const int tx = threadIdx.x & 15, ty = threadIdx.x >> 4;
#pragma unroll
  for (int i = 0; i < 4; i++) {
    f4 v;
#pragma unroll
    for (int j = 0; j < 4; j++) v[j] = acc[i][j];
    int row = mt * 64 + ty * 4 + i;
    int col = nt * 64 + tx * 4;
    for (int h = 0; h < HH; h++)
      *(f4*)&net[(size_t)h * 1048576 + row * 256 + col] = v;
  }
}

// ---------------------------------------------------------------------------
// Weight prep (per t): transpose + split into f16 hi/lo, layout [n][k(256)].
// ---------------------------------------------------------------------------
__global__ __launch_bounds__(256) void k_prep(
    const float* __restrict__ Wq, const float* __restrict__ Wk,
    const float* __restrict__ Wv, const float* __restrict__ Wd,
    _Float16* __restrict__ oh, _Float16* __restrict__ ol, int t)
{
  __shared__ __align__(16) _Float16 Th[64][LHS];
  __shared__ __align__(16) _Float16 Tl[64][LHS];
  const int xb = blockIdx.x, kb = blockIdx.y, h = blockIdx.z;
  const int tid = threadIdx.x;
  const float* src; int N, nb; size_t dbase;
  if (xb == 0)      { src = Wq; N = 64;  nb = 0;      dbase = (size_t)h * 16384; }
  else if (xb == 1) { src = Wk; N = 64;  nb = 0;      dbase = 131072 + (size_t)h * 16384; }
  else if (xb < 6)  { src = Wv; N = 256; nb = xb - 2; dbase = 262144 + (size_t)h * 65536; }
  else              { src = Wd; N = 256; nb = xb - 6; dbase = 786432 + (size_t)h * 65536; }
  src += (size_t)(h * TT + t) * 256 * N;
#pragma unroll
  for (int i = 0; i < 4; i++) {
    int fi = tid + i * 256;
    int r = fi >> 4, c4 = fi & 15;
    f4 w = *(const f4*)&src[(size_t)(kb * 64 + r) * N + nb * 64 + c4 * 4];
    h4 hv, lv;
#pragma unroll
    for (int j = 0; j < 4; j++) {
      _Float16 hi = (_Float16)w[j];
      hv[j] = hi;
      lv[j] = (_Float16)((w[j] - (float)hi) * 2048.f);
    }
    *(h4*)&Th[r][c4 * 4] = hv;
    *(h4*)&Tl[r][c4 * 4] = lv;
  }
  __syncthreads();
#pragma unroll
  for (int i = 0; i < 4; i++) {
    int fo = tid + i * 256;
    int nr = fo >> 4, k4 = fo & 15;
    h4 hv, lv;
#pragma unroll
    for (int j = 0; j < 4; j++) { hv[j] = Th[k4 * 4 + j][nr]; lv[j] = Tl[k4 * 4 + j][nr]; }
    size_t d = dbase + (size_t)(nb * 64 + nr) * 256 + kb * 64 + k4 * 4;
    *(h4*)&oh[d] = hv;
    *(h4*)&ol[d] = lv;
  }
}

// ---------------------------------------------------------------------------
// A-tile staging with on-the-fly per-column affine (BN fold).
// ---------------------------------------------------------------------------
__device__ __forceinline__ void stage_issue_aff(
    const float* __restrict__ A, const float* __restrict__ ag,
    const float* __restrict__ ab, int kc, int tid, f4 w[4])
{
#pragma unroll
  for (int i = 0; i < 4; i++) {
    int fi = tid + i * 256;
    int r = fi >> 4, c4 = fi & 15;
    f4 raw = *(const f4*)&A[(size_t)r * 256 + kc * 64 + c4 * 4];
    f4 g = *(const f4*)&ag[kc * 64 + c4 * 4];
    f4 b = *(const f4*)&ab[kc * 64 + c4 * 4];
#pragma unroll
    for (int j = 0; j < 4; j++) w[i][j] = fmaf(raw[j], g[j], b[j]);
  }
}
__device__ __forceinline__ void stage_write(
    const f4 w[4], int tid, _Float16 (*Ah)[LHS], _Float16 (*Al)[LHS])
{
#pragma unroll
  for (int i = 0; i < 4; i++) {
    int fi = tid + i * 256;
    int r = fi >> 4, c4 = fi & 15;
    h4 hv, lv;
#pragma unroll
    for (int j = 0; j < 4; j++) {
      _Float16 hi = (_Float16)w[i][j];
      hv[j] = hi;
      lv[j] = (_Float16)((w[i][j] - (float)hi) * 2048.f);
    }
    *(h4*)&Ah[r][c4 * 4] = hv;
    *(h4*)&Al[r][c4 * 4] = lv;
  }
}

// ---------------------------------------------------------------------------
// QKV GEMM (split halves): one block per (mt, h, half); half 0 = {q,k,v0},
// half 1 = {v1,v2,v3}. grid 1024, XCD-swizzled so XCD x owns h == x.
// 4 blocks/CU co-resident (LDS 17.4 KB), 5 barriers/block.
// ---------------------------------------------------------------------------
__global__ __launch_bounds__(256) void k_mm_qkv(
    const float* __restrict__ net,
    const float* __restrict__ affg, const float* __restrict__ affb,
    const _Float16* __restrict__ wph, const _Float16* __restrict__ wpl,
    _Float16* __restrict__ qph, _Float16* __restrict__ qpl,
    _Float16* __restrict__ kph, _Float16* __restrict__ kpl,
    short* __restrict__ vth, short* __restrict__ vtl)
{
  __shared__ __align__(16) _Float16 Ah[2][64][LHS];
  __shared__ __align__(16) _Float16 Al[2][64][LHS];
  const int logical = xcd_swz1024(blockIdx.x);
  const int mt = logical & 63, hh = logical >> 6;
  const int h = hh >> 1, half = hh & 1;
  const int tid = threadIdx.x, wv = tid >> 6, lane = tid & 63;
  const int ln = lane & 15, quad = lane >> 4;
  const float* A = net + (size_t)h * 1048576 + (size_t)mt * 64 * 256;
  const float* ag = affg + h * 256;
  const float* ab = affb + h * 256;

  size_t bb[3];
#pragma unroll
  for (int j = 0; j < 3; j++) {
    int nt = half * 3 + j;
    if (nt == 0)      bb[j] = (size_t)h * 16384;
    else if (nt == 1) bb[j] = 131072 + (size_t)h * 16384;
    else              bb[j] = 262144 + (size_t)h * 65536 + (size_t)(nt - 2) * 16384;
    bb[j] += (size_t)(wv * 16 + ln) * 256;
  }

  f4 mn[3][4], cr[3][4];
#pragma unroll
  for (int j = 0; j < 3; j++)
#pragma unroll
    for (int mf = 0; mf < 4; mf++) {
      mn[j][mf] = (f4){0.f, 0.f, 0.f, 0.f};
      cr[j][mf] = (f4){0.f, 0.f, 0.f, 0.f};
    }

  f4 w[4];
  stage_issue_aff(A, ag, ab, 0, tid, w);
  stage_write(w, tid, Ah[0], Al[0]);
  __syncthreads();

  for (int kc = 0; kc < 4; kc++) {
    const int buf = kc & 1;
    if (kc < 3) stage_issue_aff(A, ag, ab, kc + 1, tid, w);
#pragma unroll
    for (int j = 0; j < 3; j++) {
      const _Float16* bh = wph + bb[j] + kc * 64;
      const _Float16* bl = wpl + bb[j] + kc * 64;
      h8 bh0 = *(const h8*)&bh[quad * 8];
      h8 bh1 = *(const h8*)&bh[32 + quad * 8];
      h8 bl0 = *(const h8*)&bl[quad * 8];
      h8 bl1 = *(const h8*)&bl[32 + quad * 8];
#pragma unroll
      for (int mf = 0; mf < 4; mf++) {
        h8 ah0 = *(const h8*)&Ah[buf][mf * 16 + ln][quad * 8];
        h8 ah1 = *(const h8*)&Ah[buf][mf * 16 + ln][32 + quad * 8];
        h8 al0 = *(const h8*)&Al[buf][mf * 16 + ln][quad * 8];
        h8 al1 = *(const h8*)&Al[buf][mf * 16 + ln][32 + quad * 8];
        mn[j][mf] = __builtin_amdgcn_mfma_f32_16x16x32_f16(ah0, bh0, mn[j][mf], 0, 0, 0);
        mn[j][mf] = __builtin_amdgcn_mfma_f32_16x16x32_f16(ah1, bh1, mn[j][mf], 0, 0, 0);
        cr[j][mf] = __builtin_amdgcn_mfma_f32_16x16x32_f16(ah0, bl0, cr[j][mf], 0, 0, 0);
        cr[j][mf] = __builtin_amdgcn_mfma_f32_16x16x32_f16(ah1, bl1, cr[j][mf], 0, 0, 0);
        cr[j][mf] = __builtin_amdgcn_mfma_f32_16x16x32_f16(al0, bh0, cr[j][mf], 0, 0, 0);
        cr[j][mf] = __builtin_amdgcn_mfma_f32_16x16x32_f16(al1, bh1, cr[j][mf], 0, 0, 0);
      }
    }
    if (kc < 3) stage_write(w, tid, Ah[buf ^ 1], Al[buf ^ 1]);
    __syncthreads();
  }

#pragma unroll
  for (int j = 0; j < 3; j++) {
    int nt = half * 3 + j;
    if (nt <= 1) {
      _Float16* dh = (nt == 0) ? qph : kph;
      _Float16* dl = (nt == 0) ? qpl : kpl;
      int col = wv * 16 + ln;
#pragma unroll
      for (int mf = 0; mf < 4; mf++)
#pragma unroll
        for (int r = 0; r < 4; r++) {
          int row = mt * 64 + mf * 16 + quad * 4 + r;
          int b_ = row >> 10, sI = row & 1023;
          float v = mn[j][mf][r] + cr[j][mf][r] * INV2048;
          _Float16 hi = (_Float16)v;
          size_t idx = ((size_t)(h * 4 + b_) * 1024 + sI) * 64 + col;
          dh[idx] = hi;
          dl[idx] = (_Float16)((v - (float)hi) * 2048.f);
        }
    } else {
      int c = (nt - 2) * 64 + wv * 16 + ln;
#pragma unroll
      for (int mf = 0; mf < 4; mf++)
#pragma unroll
        for (int r = 0; r < 4; r++) {
          int row = mt * 64 + mf * 16 + quad * 4 + r;
          int b_ = row >> 10, sI = row & 1023;
          float v = mn[j][mf][r] + cr[j][mf][r] * INV2048;
          short hi = f2bf(v);
          size_t idx = ((size_t)(h * 4 + b_) * 256 + c) * 1024 + sI;
          vth[idx] = hi;
          vtl[idx] = f2bf(v - bf2f(hi));
        }
    }
  }
}

// ---------------------------------------------------------------------------
// Dense GEMM (split halves) + fused BN1-apply + residual + BN2-stats.
// One block per (mt, h, half); half = 2 col-groups. grid 1024, XCD-swizzled.
// ---------------------------------------------------------------------------
__global__ __launch_bounds__(256) void k_mm_dense(
    const float* __restrict__ buf1,
    const float* __restrict__ affg, const float* __restrict__ affb,
    const _Float16* __restrict__ wph, const _Float16* __restrict__ wpl,
    float* __restrict__ buf2, float* __restrict__ st)
{
  __shared__ __align__(16) _Float16 Ah[2][64][LHS];
  __shared__ __align__(16) _Float16 Al[2][64][LHS];
  const int logical = xcd_swz1024(blockIdx.x);
  const int mt = logical & 63, hh = logical >> 6;
  const int h = hh >> 1, half = hh & 1;
  const int tid = threadIdx.x, wv = tid >> 6, lane = tid & 63;
  const int ln = lane & 15, quad = lane >> 4;
  const float* a1 = buf1 + (size_t)h * 1048576;
  float* o2 = buf2 + (size_t)h * 1048576;
  const float* A = a1 + (size_t)mt * 64 * 256;
  const float* ag = affg + h * 256;
  const float* ab = affb + h * 256;

  size_t bb[2];
#pragma unroll
  for (int j = 0; j < 2; j++) {
    int nt = half * 2 + j;
    bb[j] = 786432 + (size_t)h * 65536 + (size_t)nt * 16384
          + (size_t)(wv * 16 + ln) * 256;
  }

  f4 mn[2][4], cr[2][4];
#pragma unroll
  for (int j = 0; j < 2; j++)
#pragma unroll
    for (int mf = 0; mf < 4; mf++) {
      mn[j][mf] = (f4){0.f, 0.f, 0.f, 0.f};
      cr[j][mf] = (f4){0.f, 0.f, 0.f, 0.f};
    }

  f4 w[4];
  stage_issue_aff(A, ag, ab, 0, tid, w);
  stage_write(w, tid, Ah[0], Al[0]);
  __syncthreads();

  for (int kc = 0; kc < 4; kc++) {
    const int buf = kc & 1;
    if (kc < 3) stage_issue_aff(A, ag, ab, kc + 1, tid, w);
#pragma unroll
    for (int j = 0; j < 2; j++) {
      const _Float16* bh = wph + bb[j] + kc * 64;
      const _Float16* bl = wpl + bb[j] + kc * 64;
      h8 bh0 = *(const h8*)&bh[quad * 8];
      h8 bh1 = *(const h8*)&bh[32 + quad * 8];
      h8 bl0 = *(const h8*)&bl[quad * 8];
      h8 bl1 = *(const h8*)&bl[32 + quad * 8];
#pragma unroll
      for (int mf = 0; mf < 4; mf++) {
        h8 ah0 = *(const h8*)&Ah[buf][mf * 16 + ln][quad * 8];
        h8 ah1 = *(const h8*)&Ah[buf][mf * 16 + ln][32 + quad * 8];
        h8 al0 = *(const h8*)&Al[buf][mf * 16 + ln][quad * 8];
        h8 al1 = *(const h8*)&Al[buf][mf * 16 + ln][32 + quad * 8];
        mn[j][mf] = __builtin_amdgcn_mfma_f32_16x16x32_f16(ah0, bh0, mn[j][mf], 0, 0, 0);
        mn[j][mf] = __builtin_amdgcn_mfma_f32_16x16x32_f16(ah1, bh1, mn[j][mf], 0, 0, 0);
        cr[j][mf] = __builtin_amdgcn_mfma_f32_16x16x32_f16(ah0, bl0, cr[j][mf], 0, 0, 0);
        cr[j][mf] = __builtin_amdgcn_mfma_f32_16x16x32_f16(ah1, bl1, cr[j][mf], 0, 0, 0);
        cr[j][mf] = __builtin_amdgcn_mfma_f32_16x16x32_f16(al0, bh0, cr[j][mf], 0, 0, 0);
        cr[j][mf] = __builtin_amdgcn_mfma_f32_16x16x32_f16(al1, bh1, cr[j][mf], 0, 0, 0);
      }
    }
    if (kc < 3) stage_write(w, tid, Ah[buf ^ 1], Al[buf ^ 1]);
    __syncthreads();
  }

#pragma unroll
  for (int j = 0; j < 2; j++) {
    int nt = half * 2 + j;
    int col = nt * 64 + wv * 16 + ln;
    float gc = ag[col], bc = ab[col];
    float s1 = 0.f, s2 = 0.f;
#pragma unroll
    for (int mf = 0; mf < 4; mf++)
#pragma unroll
      for (int r = 0; r < 4; r++) {
        int row = mt * 64 + mf * 16 + quad * 4 + r;
        size_t idx = (size_t)row * 256 + col;
        float v = mn[j][mf][r] + cr[j][mf][r] * INV2048;
        float yv = fmaf(a1[idx], gc, bc) + fmaxf(v, 0.f);
        o2[idx] = yv;
        s1 += yv; s2 += yv * yv;
      }
    s1 += __shfl_xor(s1, 16, 64); s1 += __shfl_xor(s1, 32, 64);
    s2 += __shfl_xor(s2, 16, 64); s2 += __shfl_xor(s2, 32, 64);
    if (quad == 0) {
      atomicAdd(&st[(h * 256 + col) * 2],     s1);
      atomicAdd(&st[(h * 256 + col) * 2 + 1], s2);
    }
  }
}

// ---------------------------------------------------------------------------
// Flash attention v11: quad-buffered V (one buffer per chunk) cuts barriers
// to 4/kt (B1, B2, + barrier after odd PV phases only); setprio around MFMA
// clusters (T5). LDS 80 KB = K/P overlay 16 + V 64 -> still 2 blocks/CU.
// Write/read separation: buf[(c4+2)&3] written phase c4, read 2 phases
// later; barriers after phases 1,3 separate every pair (incl. K prefetch
// at phase 3 vs P-frag reads before phase 0). XCD swizzle as v10.
// grid (512 1D).
// ---------------------------------------------------------------------------
__global__ __launch_bounds__(256, 2) void k_attn(
    const _Float16* __restrict__ qfh, const _Float16* __restrict__ qfl,
    const _Float16* __restrict__ kfh, const _Float16* __restrict__ kfl,
    const short* __restrict__ vth, const short* __restrict__ vtl,
    const float* __restrict__ resid,
    const float* __restrict__ affg, const float* __restrict__ affb,
    float* __restrict__ st, float* __restrict__ obuf)
{
  // AB0: Kh <-> Ph ; AB1: Kl <-> Pl  (8 KB each, swizzled [64][64])
  __shared__ __align__(16) short AB0[64][64];     // 8 KB
  __shared__ __align__(16) short AB1[64][64];     // 8 KB
  __shared__ __align__(16) short VhS[4][64][64];  // 32 KB (one buf per chunk)
  __shared__ __align__(16) short VlS[4][64][64];  // 32 KB  => 80 KB total

  const int logical = xcd_swz512(blockIdx.x);
  const int qt = logical & 15, hb = logical >> 4;
  const int b = hb & 3, h = hb >> 2;
  const int tid = threadIdx.x;
  const int wv = tid >> 6, lane = tid & 63, ln = lane & 15, quad = lane >> 4;
  const int swz = (ln & 7) << 3;

  const _Float16* qgh = qfh + ((size_t)hb * 1024 + qt * 64 + wv * 16 + ln) * 64;
  const _Float16* qgl = qfl + ((size_t)hb * 1024 + qt * 64 + wv * 16 + ln) * 64;
  h8 aqh0 = *(const h8*)&qgh[quad * 8];
  h8 aqh1 = *(const h8*)&qgh[32 + quad * 8];
  h8 aql0 = *(const h8*)&qgl[quad * 8];
  h8 aql1 = *(const h8*)&qgl[32 + quad * 8];

  const _Float16* kgh = kfh + (size_t)hb * 65536;   // [1024 s][64 kd]
  const _Float16* kgl = kfl + (size_t)hb * 65536;
  const short* vhg = vth + (size_t)hb * 262144;     // [256 vcol][1024 s]
  const short* vlg = vtl + (size_t)hb * 262144;

  float m[4] = {-1e30f, -1e30f, -1e30f, -1e30f};
  float l[4] = {0.f, 0.f, 0.f, 0.f};
  f4 O[16];
#pragma unroll
  for (int nt = 0; nt < 16; nt++) O[nt] = (f4){0.f, 0.f, 0.f, 0.f};

  // ---- prologue: K(0) into AB; V(kt=0) chunks 0,1 into bufs 0,1 ----
#pragma unroll
  for (int i = 0; i < 2; i++) {
    int e = tid + i * 256;
    int r = e >> 3, c8 = e & 7;
    int cc = (c8 * 8) ^ ((r & 7) << 3);
    *(h8*)&AB0[r][cc] = *(const h8*)&kgh[(size_t)r * 64 + c8 * 8];
    *(h8*)&AB1[r][cc] = *(const h8*)&kgl[(size_t)r * 64 + c8 * 8];
  }
#pragma unroll
  for (int ch = 0; ch < 2; ch++)
#pragma unroll
    for (int i = 0; i < 2; i++) {
      int e = tid + i * 256;
      int vc = e >> 3, fc = e & 7;
      int cc = (fc * 8) ^ ((vc & 7) << 3);
      size_t g = (size_t)(ch * 64 + vc) * 1024 + fc * 8;
      *(bf8*)&VhS[ch][vc][cc] = *(const bf8*)&vhg[g];
      *(bf8*)&VlS[ch][vc][cc] = *(const bf8*)&vlg[g];
    }
  __syncthreads();

  for (int kt = 0; kt < 16; kt++) {
    // ---- QK^T: K frags from AB (swizzled) ----
    f4 sv[4];
    __builtin_amdgcn_s_setprio(1);
#pragma unroll
    for (int nf = 0; nf < 4; nf++) {
      int row = nf * 16 + ln;
      h8 bkh0 = *(const h8*)&AB0[row][(quad * 8) ^ swz];
      h8 bkh1 = *(const h8*)&AB0[row][(32 + quad * 8) ^ swz];
      h8 bkl0 = *(const h8*)&AB1[row][(quad * 8) ^ swz];
      h8 bkl1 = *(const h8*)&AB1[row][(32 + quad * 8) ^ swz];
      f4 mn = (f4){0.f, 0.f, 0.f, 0.f};
      f4 cr = (f4){0.f, 0.f, 0.f, 0.f};
      mn = __builtin_amdgcn_mfma_f32_16x16x32_f16(aqh0, bkh0, mn, 0, 0, 0);
      mn = __builtin_amdgcn_mfma_f32_16x16x32_f16(aqh1, bkh1, mn, 0, 0, 0);
      cr = __builtin_amdgcn_mfma_f32_16x16x32_f16(aqh0, bkl0, cr, 0, 0, 0);
      cr = __builtin_amdgcn_mfma_f32_16x16x32_f16(aqh1, bkl1, cr, 0, 0, 0);
      cr = __builtin_amdgcn_mfma_f32_16x16x32_f16(aql0, bkh0, cr, 0, 0, 0);
      cr = __builtin_amdgcn_mfma_f32_16x16x32_f16(aql1, bkh1, cr, 0, 0, 0);
#pragma unroll
      for (int r = 0; r < 4; r++) sv[nf][r] = (mn[r] + cr[r] * INV2048) * SCL;
    }
    __builtin_amdgcn_s_setprio(0);

    // barrier: all waves done READING K before P overwrites the region.
    __syncthreads();   // B1

    // ---- online softmax with defer-max (T13, THR=8) ----
    float mloc[4];
#pragma unroll
    for (int r = 0; r < 4; r++) {
      float v0 = fmaxf(fmaxf(sv[0][r], sv[1][r]), fmaxf(sv[2][r], sv[3][r]));
#pragma unroll
      for (int d = 1; d < 16; d <<= 1)
        v0 = fmaxf(v0, __shfl_xor(v0, d, 64));
      mloc[r] = v0;
    }
    float growth = fmaxf(fmaxf(mloc[0] - m[0], mloc[1] - m[1]),
                         fmaxf(mloc[2] - m[2], mloc[3] - m[3]));
    if (__any(growth > 8.f)) {
      float alpha[4];
#pragma unroll
      for (int r = 0; r < 4; r++) {
        float mnew = fmaxf(m[r], mloc[r]);
        alpha[r] = __expf(m[r] - mnew);
        m[r] = mnew;
        l[r] *= alpha[r];
      }
#pragma unroll
      for (int nt = 0; nt < 16; nt++)
#pragma unroll
        for (int i = 0; i < 4; i++) O[nt][i] *= alpha[i];
    }
#pragma unroll
    for (int r = 0; r < 4; r++) {
      float ls = 0.f;
#pragma unroll
      for (int nf = 0; nf < 4; nf++) {
        float p = __expf(sv[nf][r] - m[r]);
        sv[nf][r] = p;
        ls += p;
      }
#pragma unroll
      for (int d = 1; d < 16; d <<= 1) ls += __shfl_xor(ls, d, 64);
      l[r] += ls;
    }

    // ---- publish P into AB (swizzled; own rows) ----
#pragma unroll
    for (int nf = 0; nf < 4; nf++)
#pragma unroll
      for (int r = 0; r < 4; r++) {
        int row = wv * 16 + quad * 4 + r;
        int c = (nf * 16 + ln) ^ ((row & 7) << 3);
        float p = sv[nf][r];
        short hi = f2bf(p);
        AB0[row][c] = hi;
        AB1[row][c] = f2bf(p - bf2f(hi));
      }
    __syncthreads();   // B2: P ready

    // ---- P fragments (own 16 rows); AB dead for P after this ----
    bf8 ph0 = *(const bf8*)&AB0[wv * 16 + ln][(quad * 8) ^ swz];
    bf8 ph1 = *(const bf8*)&AB0[wv * 16 + ln][(32 + quad * 8) ^ swz];
    bf8 pl0 = *(const bf8*)&AB1[wv * 16 + ln][(quad * 8) ^ swz];
    bf8 pl1 = *(const bf8*)&AB1[wv * 16 + ln][(32 + quad * 8) ^ swz];

    for (int c4 = 0; c4 < 4; c4++) {
      const bool haveNext = (c4 < 2) || (kt < 15);
      const int nkt = (c4 < 2) ? kt : kt + 1;
      const int nch = (c4 < 2) ? c4 + 2 : c4 - 2;
      const int nbuf = (c4 + 2) & 3;
      const bool pfK = (c4 == 3) && (kt < 15);

      const int vc0 = tid >> 3, fc0 = tid & 7;
      const int vc1 = vc0 + 32;
      bf8 fvh0, fvh1, fvl0, fvl1;
      if (haveNext) {
        size_t g0 = (size_t)(nch * 64 + vc0) * 1024 + nkt * 64 + fc0 * 8;
        size_t g1 = (size_t)(nch * 64 + vc1) * 1024 + nkt * 64 + fc0 * 8;
        fvh0 = *(const bf8*)&vhg[g0]; fvl0 = *(const bf8*)&vlg[g0];
        fvh1 = *(const bf8*)&vhg[g1]; fvl1 = *(const bf8*)&vlg[g1];
      }
      h8 fkh0, fkh1, fkl0, fkl1;
      if (pfK) {
        size_t g0 = (size_t)((kt + 1) * 64 + vc0) * 64 + fc0 * 8;
        size_t g1 = (size_t)((kt + 1) * 64 + vc1) * 64 + fc0 * 8;
        fkh0 = *(const h8*)&kgh[g0]; fkl0 = *(const h8*)&kgl[g0];
        fkh1 = *(const h8*)&kgh[g1]; fkl1 = *(const h8*)&kgl[g1];
      }

      __builtin_amdgcn_s_setprio(1);
#pragma unroll
      for (int n2 = 0; n2 < 4; n2++) {
        int nt = c4 * 4 + n2;
        int vrow = n2 * 16 + ln;
        bf8 vh0 = *(const bf8*)&VhS[c4][vrow][(quad * 8) ^ swz];
        bf8 vh1 = *(const bf8*)&VhS[c4][vrow][(32 + quad * 8) ^ swz];
        bf8 vl0 = *(const bf8*)&VlS[c4][vrow][(quad * 8) ^ swz];
        bf8 vl1 = *(const bf8*)&VlS[c4][vrow][(32 + quad * 8) ^ swz];
        O[nt] = __builtin_amdgcn_mfma_f32_16x16x32_bf16(ph0, vh0, O[nt], 0, 0, 0);
        O[nt] = __builtin_amdgcn_mfma_f32_16x16x32_bf16(ph1, vh1, O[nt], 0, 0, 0);
        O[nt] = __builtin_amdgcn_mfma_f32_16x16x32_bf16(ph0, vl0, O[nt], 0, 0, 0);
        O[nt] = __builtin_amdgcn_mfma_f32_16x16x32_bf16(ph1, vl1, O[nt], 0, 0, 0);
        O[nt] = __builtin_amdgcn_mfma_f32_16x16x32_bf16(pl0, vh0, O[nt], 0, 0, 0);
        O[nt] = __builtin_amdgcn_mfma_f32_16x16x32_bf16(pl1, vh1, O[nt], 0, 0, 0);
      }
      __builtin_amdgcn_s_setprio(0);

      if (haveNext) {
        int cc0 = (fc0 * 8) ^ ((vc0 & 7) << 3);
        int cc1 = (fc0 * 8) ^ ((vc1 & 7) << 3);
        *(bf8*)&VhS[nbuf][vc0][cc0] = fvh0;
        *(bf8*)&VlS[nbuf][vc0][cc0] = fvl0;
        *(bf8*)&VhS[nbuf][vc1][cc1] = fvh1;
        *(bf8*)&VlS[nbuf][vc1][cc1] = fvl1;
      }
      if (pfK) {
        // AB dead for P (frag reads done before phase 0; barrier after
        // phase 1 separates) -> free for K(kt+1).
        int cc0 = (fc0 * 8) ^ ((vc0 & 7) << 3);
        int cc1 = (fc0 * 8) ^ ((vc1 & 7) << 3);
        *(h8*)&AB0[vc0][cc0] = fkh0;
        *(h8*)&AB1[vc0][cc0] = fkl0;
        *(h8*)&AB0[vc1][cc1] = fkh1;
        *(h8*)&AB1[vc1][cc1] = fkl1;
      }
      if (c4 & 1) __syncthreads();   // barriers only after phases 1 and 3
    }
  }

  // ---- fused epilogue: y1 = affine(resid) + O/l -> buf1; BN1 stats ----
  const float* rg = affg + h * 256;
  const float* rb = affb + h * 256;
  const float* rs = resid + (size_t)h * 1048576
                  + (size_t)(b * 1024 + qt * 64 + wv * 16 + quad * 4) * 256;
  float* ds = obuf + (size_t)h * 1048576
            + (size_t)(b * 1024 + qt * 64 + wv * 16 + quad * 4) * 256;
  float linv[4];
#pragma unroll
  for (int r = 0; r < 4; r++) linv[r] = 1.f / l[r];

  float* S1 = (float*)&AB0[0][0];   // AB free after the loop
  float* S2 = (float*)&AB1[0][0];
#pragma unroll
  for (int nt = 0; nt < 16; nt++) {
    int c = nt * 16 + ln;
    float gc = rg[c], bc = rb[c];
    float s1 = 0.f, s2 = 0.f;
#pragma unroll
    for (int r = 0; r < 4; r++) {
      float yv = fmaf(rs[r * 256 + c], gc, bc) + O[nt][r] * linv[r];
      ds[r * 256 + c] = yv;
      s1 += yv; s2 += yv * yv;
    }
    s1 += __shfl_xor(s1, 16, 64); s1 += __shfl_xor(s1, 32, 64);
    s2 += __shfl_xor(s2, 16, 64); s2 += __shfl_xor(s2, 32, 64);
    if (quad == 0) { S1[wv * 256 + c] = s1; S2[wv * 256 + c] = s2; }
  }
  __syncthreads();
  if (tid < 256) {
    float a1 = S1[tid] + S1[256 + tid] + S1[512 + tid] + S1[768 + tid];
    float a2 = S2[tid] + S2[256 + tid] + S2[512 + tid] + S2[768 + tid];
    atomicAdd(&st[(h * 256 + tid) * 2],     a1);
    atomicAdd(&st[(h * 256 + tid) * 2 + 1], a2);
  }
}

// ---------------------------------------------------------------------------
// BN apply (final t only: transposed output)
// ---------------------------------------------------------------------------
__global__ __launch_bounds__(256) void k_bnapply(
    const float* __restrict__ a, const float* __restrict__ b,
    const float* __restrict__ stats,
    const float* __restrict__ gamma, const float* __restrict__ beta,
    float* __restrict__ dst, int t, int addB, int transposed)
{
  const int h = blockIdx.y, r0 = blockIdx.x * 64, c = threadIdx.x;
  float s  = stats[(h * 256 + c) * 2];
  float s2 = stats[(h * 256 + c) * 2 + 1];
  float mean = s * (1.f / 4096.f);
  float var  = s2 * (1.f / 4096.f) - mean * mean;
  float inv  = rsqrtf(var + EPSV);
  float g  = gamma[(h * TT + t) * 256 + c] * inv;
  float bt = beta[(h * TT + t) * 256 + c];
  const float* pa = a + (size_t)h * 1048576 + r0 * 256 + c;
  const float* pb = addB ? (b + (size_t)h * 1048576 + r0 * 256 + c) : nullptr;
  for (int r = 0; r < 64; r++) {
    float y = pa[r * 256];
    if (addB) y += pb[r * 256];
    float o = (y - mean) * g + bt;
    int rg = r0 + r;
    if (transposed) dst[((size_t)rg * HH + h) * 256 + c] = o;
    else            dst[(size_t)h * 1048576 + rg * 256 + c] = o;
  }
}

// ---------------------------------------------------------------------------
extern "C" void kernel_launch(void* const* d_in, const int* in_sizes, int n_in,
                              void* d_out, int out_size, void* d_ws, size_t ws_size,
                              hipStream_t stream)
{
  const float* x   = (const float*)d_in[0];
  const float* Win = (const float*)d_in[1];
  const float* Wq  = (const float*)d_in[2];
  const float* Wk  = (const float*)d_in[3];
  const float* Wv  = (const float*)d_in[4];
  const float* Wd  = (const float*)d_in[5];
  const float* g1  = (const float*)d_in[6];
  const float* b1  = (const float*)d_in[7];
  const float* g2  = (const float*)d_in[8];
  const float* b2  = (const float*)d_in[9];
  float* out = (float*)d_out;
  float* ws  = (float*)d_ws;

  float* net   = ws;                       // buf2: pre-BN2 state (or net0)
  float* tmp   = net + 8388608;            // buf1: pre-BN1 state (y1)
  float* stats = tmp + 8388608;            // 2 phases * H*V*2 = 8192 f
  float* affg1 = stats + 8192;             // 2048 f each
  float* affb1 = affg1 + 2048;
  float* affg2 = affb1 + 2048;
  float* affb2 = affg2 + 2048;
  float* affgI = affb2 + 2048;
  float* affbI = affgI + 2048;             // ends at stats+20480 < stats+32768
  _Float16* qph = (_Float16*)(stats + 32768);  // 2,097,152 h
  _Float16* qpl = qph + 2097152;
  _Float16* kph = qpl + 2097152;
  _Float16* kpl = kph + 2097152;
  short* vth   = (short*)(kpl + 2097152);
  short* vtl   = vth + 8388608;
  _Float16* wph = (_Float16*)(vtl + 8388608);
  _Float16* wpl = wph + 1310720;

  k_init<<<dim3(8), 256, 0, stream>>>(affgI, affbI);
  k_in_dense<<<dim3(64, 4), 256, 0, stream>>>(x, Win, net);

  for (int t = 0; t < TT; t++) {
    float* st1 = stats;
    float* st2 = stats + 4096;
    hipMemsetAsync(stats, 0, 8192 * sizeof(float), stream);

    const float* cg = (t == 0) ? affgI : affg2;
    const float* cb = (t == 0) ? affbI : affb2;

    k_prep<<<dim3(10, 4, 8), 256, 0, stream>>>(Wq, Wk, Wv, Wd, wph, wpl, t);
    k_mm_qkv<<<dim3(1024), 256, 0, stream>>>(net, cg, cb, wph, wpl,
                                             qph, qpl, kph, kpl, vth, vtl);
    k_attn<<<dim3(512), 256, 0, stream>>>(qph, qpl, kph, kpl, vth, vtl,
                                          net, cg, cb, st1, tmp);
    k_affine<<<dim3(8), 256, 0, stream>>>(st1, g1, b1, t, affg1, affb1);
    k_mm_dense<<<dim3(1024), 256, 0, stream>>>(tmp, affg1, affb1, wph, wpl,
                                               net, st2);
    if (t < TT - 1)
      k_affine<<<dim3(8), 256, 0, stream>>>(st2, g2, b2, t, affg2, affb2);
    else
      k_bnapply<<<dim3(64, 8), 256, 0, stream>>>(net, nullptr, st2, g2, b2,
                                                 out, t, 0, 1);
  }
}